// Round 4
// baseline (585.720 us; speedup 1.0000x reference)
//
#include <hip/hip_runtime.h>
#include <math.h>

#define Bb 8
#define Tt 512
#define Ff 256
#define Cc 16
#define TF (Tt*Ff)
#define TROW 528
#define FROW 272
#define CELL 64
#define ROWBYTES (FROW*CELL)                       // 17408
#define BUFBYTES ((size_t)Bb*TROW*FROW*CELL)       // 73,531,392

typedef __attribute__((ext_vector_type(8))) short short8;
typedef __attribute__((ext_vector_type(4))) float f32x4;

typedef const __attribute__((address_space(1))) void* gas1_t;
typedef __attribute__((address_space(3))) void* las3_t;
#define GLOAD_LDS(g, l) __builtin_amdgcn_global_load_lds((gas1_t)(const void*)(g), (las3_t)(void*)(l), 16, 0, 0)

__device__ __forceinline__ float fast_sigmoid(float x) {
    return __builtin_amdgcn_rcpf(1.0f + __expf(-x));
}
__device__ __forceinline__ float fast_tanh(float x) {
    return 1.0f - 2.0f * __builtin_amdgcn_rcpf(__expf(2.0f * x) + 1.0f);
}

__device__ __forceinline__ unsigned short bf16_rne(float x) {
    unsigned u = __float_as_uint(x);
    u += 0x7fffu + ((u >> 16) & 1u);
    return (unsigned short)(u >> 16);
}
__device__ __forceinline__ float bf16_to_f(unsigned short h) {
    return __uint_as_float(((unsigned)h) << 16);
}
__device__ __forceinline__ f32x4 mfma_bf16(short8 a, short8 b, f32x4 c) {
    return __builtin_amdgcn_mfma_f32_16x16x32_bf16(a, b, c, 0, 0, 0);
}

// ---------- zero the halo pads of bufA and bufB (re-poisoned every launch) ----------
__global__ __launch_bounds__(256) void padzero(char* __restrict__ bufA, char* __restrict__ bufB)
{
    int idx = blockIdx.x * 256 + threadIdx.x;      // 200704 cells total
    int which = idx >= 100352;
    int r0 = which ? idx - 100352 : idx;
    int b = r0 / 12544, c = r0 - b * 12544;
    int tp, fp;
    if (c < 4352) { int row = c / 272; fp = c - row * 272; tp = row < 8 ? row : 512 + row; }
    else { int c2 = c - 4352; tp = 8 + (c2 >> 4); int fi = c2 & 15; fp = fi < 8 ? fi : 256 + fi; }
    char* base = (which ? bufB : bufA) + ((size_t)(b * TROW + tp) * FROW + fp) * CELL;
    float4 z = make_float4(0.f, 0.f, 0.f, 0.f);
    float4* p = (float4*)base;
    p[0] = z; p[1] = z; p[2] = z; p[3] = z;
}

// ---------- fold BN into weights, split bf16 hi/lo, write swizzled A-fragment layout ----------
__global__ __launch_bounds__(256) void wsetup(const float* __restrict__ w, const float* __restrict__ bias,
                       const float* __restrict__ gamma, const float* __restrict__ beta,
                       const float* __restrict__ mean, const float* __restrict__ var,
                       char* __restrict__ wpre, float* __restrict__ bpre)
{
    int tid = threadIdx.x;
    if (tid < 32) {
        float s = gamma[tid] * rsqrtf(var[tid] + 1e-5f);
        bpre[tid] = (bias[tid] - mean[tid]) * s + beta[tid];
    }
    for (int i = tid; i < 4608; i += 256) {
        int co = i / 144, r = i - co * 144;
        int ci = r / 9, tap = r - ci * 9;
        float s = gamma[co] * rsqrtf(var[co] + 1e-5f);
        float wv = w[(co * 16 + ci) * 9 + tap] * s;
        unsigned short hi = bf16_rne(wv);
        unsigned short lo = bf16_rne(wv - bf16_to_f(hi));
        int ks = tap >> 1, tp = tap & 1;
        int kl = tp * 16 + ci;
        int qq = kl >> 3, jj = kl & 7;
        int sub = qq ^ (co & 3);
        *(unsigned short*)(wpre + ((0 * 5 + ks) * 32 + co) * 64 + sub * 16 + jj * 2) = hi;
        *(unsigned short*)(wpre + ((1 * 5 + ks) * 32 + co) * 64 + sub * 16 + jj * 2) = lo;
    }
    // zero the pad half of k-step 4 (k_local 16..31), both planes
    for (int i = tid; i < 1024; i += 256) {
        int p = i >> 9, rem = i & 511;
        int co = rem >> 4, kl = 16 + (rem & 15);
        int qq = kl >> 3, jj = kl & 7;
        int sub = qq ^ (co & 3);
        *(unsigned short*)(wpre + ((p * 5 + 4) * 32 + co) * 64 + sub * 16 + jj * 2) = 0;
    }
}

// ---------- conv1 (CIN=2, dil=1): vector kernel, writes padded swizzled bf16 hi/lo layout ----------
__global__ __launch_bounds__(256)
void gate1_kernel(const float* __restrict__ x, const float* __restrict__ w,
                  const float* __restrict__ bias, const float* __restrict__ gamma,
                  const float* __restrict__ beta, const float* __restrict__ mean,
                  const float* __restrict__ var, char* __restrict__ outBuf)
{
    constexpr int CIN = 2;
    __shared__ float wlds[CIN * 32 * 9];
    const int t = blockIdx.x, b = blockIdx.y;
    const int tid = threadIdx.x;
    const int cg = tid >> 5;
    const int f0 = (tid & 31) * 8;

    for (int idx = tid; idx < CIN * 32 * 9; idx += 256) {
        int ci = idx / 288, r = idx - ci * 288;
        int cgi = r / 36, r2 = r - cgi * 36;
        int j = r2 / 9, k = r2 - j * 9;
        int co = 2 * cgi + (j & 1) + (j >> 1) * 16;
        wlds[idx] = w[(co * CIN + ci) * 9 + k];
    }
    __syncthreads();

    float bns[4], bno[4], acc[4][8];
    #pragma unroll
    for (int j = 0; j < 4; j++) {
        int c = 2 * cg + (j & 1) + (j >> 1) * 16;
        float s = gamma[c] * rsqrtf(var[c] + 1e-5f);
        bns[j] = s; bno[j] = beta[c] - mean[c] * s;
        float bi = bias[c];
        #pragma unroll
        for (int q = 0; q < 8; q++) acc[j][q] = bi;
    }

    for (int ci = 0; ci < CIN; ci++) {
        float wr[36];
        const float4* wv4 = (const float4*)(wlds + ci * 288 + cg * 36);
        #pragma unroll
        for (int v = 0; v < 9; v++) ((float4*)wr)[v] = wv4[v];
        #pragma unroll
        for (int dt = 0; dt < 3; dt++) {
            int t_in = t + dt - 1;
            bool trow = (t_in >= 0) && (t_in < Tt);
            const float* rowp = x + ((size_t)(b * CIN + ci) * Tt + (trow ? t_in : 0)) * Ff;
            float buf[16];
            #pragma unroll
            for (int v = 0; v < 4; v++) {
                int fb = f0 - 4 + v * 4;
                float4 val = make_float4(0.f, 0.f, 0.f, 0.f);
                if (trow && fb >= 0 && fb <= Ff - 4) val = *(const float4*)(rowp + fb);
                buf[v*4+0] = val.x; buf[v*4+1] = val.y; buf[v*4+2] = val.z; buf[v*4+3] = val.w;
            }
            #pragma unroll
            for (int kf = 0; kf < 3; kf++)
                #pragma unroll
                for (int j = 0; j < 4; j++) {
                    float wj = wr[j * 9 + dt * 3 + kf];
                    #pragma unroll
                    for (int q = 0; q < 8; q++)
                        acc[j][q] = fmaf(buf[4 + q + kf - 1], wj, acc[j][q]);
                }
        }
    }

    float res[2][8];
    #pragma unroll
    for (int jj = 0; jj < 2; jj++)
        #pragma unroll
        for (int q = 0; q < 8; q++) {
            float a = acc[jj][q] * bns[jj] + bno[jj];
            float g = acc[jj + 2][q] * bns[jj + 2] + bno[jj + 2];
            res[jj][q] = fast_tanh(a) * fast_sigmoid(g);
        }
    // write 2 channels (2cg, 2cg+1) hi+lo into swizzled cells
    #pragma unroll
    for (int q = 0; q < 8; q++) {
        int fp = f0 + q + 8;
        char* cell = outBuf + ((size_t)(b * TROW + t + 8) * FROW + fp) * CELL;
        unsigned short h0 = bf16_rne(res[0][q]), h1 = bf16_rne(res[1][q]);
        unsigned short l0 = bf16_rne(res[0][q] - bf16_to_f(h0));
        unsigned short l1 = bf16_rne(res[1][q] - bf16_to_f(h1));
        unsigned hw = (unsigned)h0 | ((unsigned)h1 << 16);
        unsigned lw = (unsigned)l0 | ((unsigned)l1 << 16);
        int inner = (4 * cg) & 15;
        int sub_hi = (cg >> 2) ^ (fp & 3);
        int sub_lo = (2 + (cg >> 2)) ^ (fp & 3);
        *(unsigned*)(cell + sub_hi * 16 + inner) = hw;
        *(unsigned*)(cell + sub_lo * 16 + inner) = lw;
    }
}

// ---------- convs 2-4: MFMA implicit GEMM, bf16 hi/lo 3-pass ----------
template<int DIL, int WRITE_F32>
__global__ __launch_bounds__(256, 2)
void gate_mfma(const char* __restrict__ actIn, const char* __restrict__ wpre,
               const float* __restrict__ bpre, char* __restrict__ outBuf)
{
    __shared__ char actL[3 * ROWBYTES];    // 52224 B
    const int t = blockIdx.x, b = blockIdx.y;
    const int tid = threadIdx.x;
    const int wv = tid >> 6, lane = tid & 63;
    const int n = lane & 15, q = lane >> 4;

    // A-fragments (weights) from global (L2-hot), registers
    short8 aH[5][2], aL[5][2];
    #pragma unroll
    for (int ks = 0; ks < 5; ks++)
        #pragma unroll
        for (int ct = 0; ct < 2; ct++) {
            int co = ct * 16 + n;
            int sub = q ^ (co & 3);
            aH[ks][ct] = *(const short8*)(wpre + (size_t)((0 * 5 + ks) * 32 + co) * 64 + sub * 16);
            aL[ks][ct] = *(const short8*)(wpre + (size_t)((5 + ks) * 32 + co) * 64 + sub * 16);
        }

    // stage 3 act rows (t-d, t, t+d), contiguous 1088 chunks each
    #pragma unroll
    for (int r = 0; r < 3; r++) {
        int tp = t + 8 + (r - 1) * DIL;
        const char* src = actIn + ((size_t)(b * TROW + tp) * FROW) * CELL;
        char* dst = actL + r * ROWBYTES;
        #pragma unroll
        for (int i = 0; i < 4; i++)
            GLOAD_LDS(src + (i * 256 + tid) * 16, dst + (i * 256 + wv * 64) * 16);
        if (tid < 64)
            GLOAD_LDS(src + (1024 + lane) * 16, dst + 1024 * 16);
    }
    __syncthreads();

    const int fb = wv * 64;
    f32x4 acc[4][2] = {};

    #pragma unroll
    for (int ks = 0; ks < 5; ks++) {
        const int tapA = 2 * ks;
        const int tapB = (2 * ks + 1 > 8) ? 8 : 2 * ks + 1;
        const int rowA = tapA / 3, dfA = (tapA % 3 - 1) * DIL;
        const int rowB = tapB / 3, dfB = (tapB % 3 - 1) * DIL;
        int tapSel = q >> 1;
        int row = tapSel ? rowB : rowA;
        int df  = tapSel ? dfB : dfA;
        int cih = q & 1;
        const char* rbase = actL + row * ROWBYTES;
        #pragma unroll
        for (int nt = 0; nt < 4; nt++) {
            int fp = fb + nt * 16 + n + 8 + df;
            const char* cell = rbase + fp * CELL;
            short8 bH = *(const short8*)(cell + ((cih) ^ (fp & 3)) * 16);
            short8 bL = *(const short8*)(cell + ((2 + cih) ^ (fp & 3)) * 16);
            #pragma unroll
            for (int ct = 0; ct < 2; ct++) {
                acc[nt][ct] = mfma_bf16(aH[ks][ct], bH, acc[nt][ct]);
                acc[nt][ct] = mfma_bf16(aL[ks][ct], bH, acc[nt][ct]);
                acc[nt][ct] = mfma_bf16(aH[ks][ct], bL, acc[nt][ct]);
            }
        }
    }

    // epilogue: GLU, then store
    float4 bA = *(const float4*)(bpre + q * 4);
    float4 bG = *(const float4*)(bpre + 16 + q * 4);
    #pragma unroll
    for (int nt = 0; nt < 4; nt++) {
        float r[4];
        r[0] = fast_tanh(acc[nt][0].x + bA.x) * fast_sigmoid(acc[nt][1].x + bG.x);
        r[1] = fast_tanh(acc[nt][0].y + bA.y) * fast_sigmoid(acc[nt][1].y + bG.y);
        r[2] = fast_tanh(acc[nt][0].z + bA.z) * fast_sigmoid(acc[nt][1].z + bG.z);
        r[3] = fast_tanh(acc[nt][0].w + bA.w) * fast_sigmoid(acc[nt][1].w + bG.w);
        int f = fb + nt * 16 + n;
        if (WRITE_F32) {
            float* gp = (float*)outBuf;
            #pragma unroll
            for (int j = 0; j < 4; j++)
                gp[((size_t)(b * 16 + q * 4 + j) * Tt + t) * Ff + f] = r[j];
        } else {
            int fp = f + 8;
            char* cell = outBuf + ((size_t)(b * TROW + t + 8) * FROW + fp) * CELL;
            unsigned short h[4], l[4];
            #pragma unroll
            for (int j = 0; j < 4; j++) {
                h[j] = bf16_rne(r[j]);
                l[j] = bf16_rne(r[j] - bf16_to_f(h[j]));
            }
            uint2 hw, lw;
            hw.x = (unsigned)h[0] | ((unsigned)h[1] << 16);
            hw.y = (unsigned)h[2] | ((unsigned)h[3] << 16);
            lw.x = (unsigned)l[0] | ((unsigned)l[1] << 16);
            lw.y = (unsigned)l[2] | ((unsigned)l[3] << 16);
            int inner = (q & 1) * 8;
            *(uint2*)(cell + (((q >> 1) ^ (fp & 3)) * 16) + inner) = hw;
            *(uint2*)(cell + (((2 + (q >> 1)) ^ (fp & 3)) * 16) + inner) = lw;
        }
    }
}

// ---------- grouped GRU (H=2) + fused out_w partial dot ----------
// Depth-16 in-place prefetch; outputs batched per 16-block so outstanding
// vmem ops stay <= 48 < 63 (vmcnt expressible -> no conservative drains).
__global__ __launch_bounds__(64)
void gru_kernel(const float* __restrict__ xin, const float* __restrict__ wih,
                const float* __restrict__ whh, const float* __restrict__ bih,
                const float* __restrict__ bhh, const float* __restrict__ out_w,
                float* __restrict__ part)
{
    const int f = (blockIdx.x & 3) * 64 + threadIdx.x;
    const int g = (blockIdx.x >> 2) & 7;
    const int b = blockIdx.x >> 5;

    float Wih[6][2], Whh[6][2], Bih[6], Bhh[6];
    #pragma unroll
    for (int k = 0; k < 6; k++) {
        Wih[k][0] = wih[g * 12 + k * 2 + 0];
        Wih[k][1] = wih[g * 12 + k * 2 + 1];
        Whh[k][0] = whh[g * 12 + k * 2 + 0];
        Whh[k][1] = whh[g * 12 + k * 2 + 1];
        Bih[k] = bih[g * 6 + k];
        Bhh[k] = bhh[g * 6 + k];
    }
    const float ow0 = out_w[2 * g], ow1 = out_w[2 * g + 1];
    const float* p0 = xin + (size_t)(b * Cc + 2 * g) * TF + f;
    const float* p1 = p0 + TF;
    float* po = part + (size_t)(b * 8 + g) * TF + f;

    float h0 = 0.f, h1 = 0.f;
    float a0[16], a1[16], outR[16];
    #pragma unroll
    for (int j = 0; j < 16; j++) { a0[j] = p0[j * Ff]; a1[j] = p1[j * Ff]; }

    for (int t0 = 0; t0 < Tt; t0 += 16) {
        const bool pf = (t0 + 16 < Tt);
        #pragma unroll
        for (int j = 0; j < 16; j++) {
            float x0 = a0[j], x1 = a1[j];
            if (pf) { a0[j] = p0[(t0 + 16 + j) * Ff]; a1[j] = p1[(t0 + 16 + j) * Ff]; }
            float gi[6], gh[6];
            #pragma unroll
            for (int k = 0; k < 6; k++) {
                gi[k] = fmaf(Wih[k][0], x0, fmaf(Wih[k][1], x1, Bih[k]));
                gh[k] = fmaf(Whh[k][0], h0, fmaf(Whh[k][1], h1, Bhh[k]));
            }
            float r0 = fast_sigmoid(gi[0] + gh[0]);
            float r1 = fast_sigmoid(gi[1] + gh[1]);
            float z0 = fast_sigmoid(gi[2] + gh[2]);
            float z1 = fast_sigmoid(gi[3] + gh[3]);
            float n0 = fast_tanh(gi[4] + r0 * gh[4]);
            float n1 = fast_tanh(gi[5] + r1 * gh[5]);
            h0 = (1.0f - z0) * n0 + z0 * h0;
            h1 = (1.0f - z1) * n1 + z1 * h1;
            outR[j] = fmaf(h0, ow0, h1 * ow1);
        }
        #pragma unroll
        for (int j = 0; j < 16; j++)
            po[(t0 + j) * Ff] = outR[j];
    }
}

__global__ __launch_bounds__(256)
void out_kernel(const float* __restrict__ part, const float* __restrict__ out_b,
                float* __restrict__ out)
{
    int idx = (blockIdx.x * 256 + threadIdx.x) * 4;
    int b = idx / TF;
    int r = idx - b * TF;
    const float4* p = (const float4*)(part + (size_t)b * 8 * TF + r);
    float ob = out_b[0];
    float4 s = make_float4(ob, ob, ob, ob);
    #pragma unroll
    for (int g = 0; g < 8; g++) {
        float4 v = p[(size_t)g * (TF / 4)];
        s.x += v.x; s.y += v.y; s.z += v.z; s.w += v.w;
    }
    *(float4*)(out + idx) = s;
}

extern "C" void kernel_launch(void* const* d_in, const int* in_sizes, int n_in,
                              void* d_out, int out_size, void* d_ws, size_t ws_size,
                              hipStream_t stream) {
    char* bufA = (char*)d_ws;
    char* bufB = bufA + BUFBYTES;
    char* wpre = bufB + BUFBYTES;
    float* bpre = (float*)(wpre + 3 * 20480);

    padzero<<<784, 256, 0, stream>>>(bufA, bufB);
    wsetup<<<1, 256, 0, stream>>>((const float*)d_in[7],  (const float*)d_in[8],  (const float*)d_in[9],
                                  (const float*)d_in[10], (const float*)d_in[11], (const float*)d_in[12],
                                  wpre, bpre);
    wsetup<<<1, 256, 0, stream>>>((const float*)d_in[13], (const float*)d_in[14], (const float*)d_in[15],
                                  (const float*)d_in[16], (const float*)d_in[17], (const float*)d_in[18],
                                  wpre + 20480, bpre + 32);
    wsetup<<<1, 256, 0, stream>>>((const float*)d_in[19], (const float*)d_in[20], (const float*)d_in[21],
                                  (const float*)d_in[22], (const float*)d_in[23], (const float*)d_in[24],
                                  wpre + 40960, bpre + 64);

    dim3 grid(Tt, Bb), blk(256);
    gate1_kernel<<<grid, blk, 0, stream>>>(
        (const float*)d_in[0], (const float*)d_in[1], (const float*)d_in[2], (const float*)d_in[3],
        (const float*)d_in[4], (const float*)d_in[5], (const float*)d_in[6], bufA);

    gate_mfma<2, 0><<<grid, blk, 0, stream>>>(bufA, wpre,        bpre,      bufB);
    gate_mfma<4, 0><<<grid, blk, 0, stream>>>(bufB, wpre + 20480, bpre + 32, bufA);
    gate_mfma<8, 1><<<grid, blk, 0, stream>>>(bufA, wpre + 40960, bpre + 64, bufB);

    // GRU reads fp32 gruIn (bufB), writes partials into bufA
    gru_kernel<<<Bb * 8 * 4, 64, 0, stream>>>(
        (const float*)bufB, (const float*)d_in[25], (const float*)d_in[26], (const float*)d_in[27],
        (const float*)d_in[28], (const float*)d_in[29], (float*)bufA);

    out_kernel<<<(Bb * TF / 4) / 256, 256, 0, stream>>>(
        (const float*)bufA, (const float*)d_in[30], (float*)d_out);
}

// Round 5
// 445.123 us; speedup vs baseline: 1.3159x; 1.3159x over previous
//
#include <hip/hip_runtime.h>
#include <math.h>

#define Bb 8
#define Tt 512
#define Ff 256
#define Cc 16
#define TF (Tt*Ff)
#define TROW 528
#define FROW 272
#define CELL 64
#define ROWBYTES (FROW*CELL)                       // 17408
#define BUFBYTES ((size_t)Bb*TROW*FROW*CELL)       // 73,531,392

typedef __attribute__((ext_vector_type(8))) short short8;
typedef __attribute__((ext_vector_type(4))) float f32x4;

typedef const __attribute__((address_space(1))) void* gas1_t;
typedef __attribute__((address_space(3))) void* las3_t;
#define GLOAD_LDS(g, l) __builtin_amdgcn_global_load_lds((gas1_t)(const void*)(g), (las3_t)(void*)(l), 16, 0, 0)

__device__ __forceinline__ float fast_sigmoid(float x) {
    return __builtin_amdgcn_rcpf(1.0f + __expf(-x));
}
__device__ __forceinline__ float fast_tanh(float x) {
    return 1.0f - 2.0f * __builtin_amdgcn_rcpf(__expf(2.0f * x) + 1.0f);
}

__device__ __forceinline__ unsigned short bf16_rne(float x) {
    unsigned u = __float_as_uint(x);
    u += 0x7fffu + ((u >> 16) & 1u);
    return (unsigned short)(u >> 16);
}
__device__ __forceinline__ float bf16_to_f(unsigned short h) {
    return __uint_as_float(((unsigned)h) << 16);
}
__device__ __forceinline__ f32x4 mfma_bf16(short8 a, short8 b, f32x4 c) {
    return __builtin_amdgcn_mfma_f32_16x16x32_bf16(a, b, c, 0, 0, 0);
}

// ---------- zero the halo pads of bufA and bufB (re-poisoned every launch) ----------
__global__ __launch_bounds__(256) void padzero(char* __restrict__ bufA, char* __restrict__ bufB)
{
    int idx = blockIdx.x * 256 + threadIdx.x;      // 200704 cells total
    int which = idx >= 100352;
    int r0 = which ? idx - 100352 : idx;
    int b = r0 / 12544, c = r0 - b * 12544;
    int tp, fp;
    if (c < 4352) { int row = c / 272; fp = c - row * 272; tp = row < 8 ? row : 512 + row; }
    else { int c2 = c - 4352; tp = 8 + (c2 >> 4); int fi = c2 & 15; fp = fi < 8 ? fi : 256 + fi; }
    char* base = (which ? bufB : bufA) + ((size_t)(b * TROW + tp) * FROW + fp) * CELL;
    float4 z = make_float4(0.f, 0.f, 0.f, 0.f);
    float4* p = (float4*)base;
    p[0] = z; p[1] = z; p[2] = z; p[3] = z;
}

// ---------- fold BN into weights, split bf16 hi/lo, write swizzled A-fragment layout ----------
__global__ __launch_bounds__(256) void wsetup(const float* __restrict__ w, const float* __restrict__ bias,
                       const float* __restrict__ gamma, const float* __restrict__ beta,
                       const float* __restrict__ mean, const float* __restrict__ var,
                       char* __restrict__ wpre, float* __restrict__ bpre)
{
    int tid = threadIdx.x;
    if (tid < 32) {
        float s = gamma[tid] * rsqrtf(var[tid] + 1e-5f);
        bpre[tid] = (bias[tid] - mean[tid]) * s + beta[tid];
    }
    for (int i = tid; i < 4608; i += 256) {
        int co = i / 144, r = i - co * 144;
        int ci = r / 9, tap = r - ci * 9;
        float s = gamma[co] * rsqrtf(var[co] + 1e-5f);
        float wv = w[(co * 16 + ci) * 9 + tap] * s;
        unsigned short hi = bf16_rne(wv);
        unsigned short lo = bf16_rne(wv - bf16_to_f(hi));
        int ks = tap >> 1, tp = tap & 1;
        int kl = tp * 16 + ci;
        int qq = kl >> 3, jj = kl & 7;
        int sub = qq ^ (co & 3);
        *(unsigned short*)(wpre + ((0 * 5 + ks) * 32 + co) * 64 + sub * 16 + jj * 2) = hi;
        *(unsigned short*)(wpre + ((1 * 5 + ks) * 32 + co) * 64 + sub * 16 + jj * 2) = lo;
    }
    // zero the pad half of k-step 4 (k_local 16..31), both planes
    for (int i = tid; i < 1024; i += 256) {
        int p = i >> 9, rem = i & 511;
        int co = rem >> 4, kl = 16 + (rem & 15);
        int qq = kl >> 3, jj = kl & 7;
        int sub = qq ^ (co & 3);
        *(unsigned short*)(wpre + ((p * 5 + 4) * 32 + co) * 64 + sub * 16 + jj * 2) = 0;
    }
}

// ---------- conv1 (CIN=2, dil=1): vector kernel, writes padded swizzled bf16 hi/lo layout ----------
__global__ __launch_bounds__(256)
void gate1_kernel(const float* __restrict__ x, const float* __restrict__ w,
                  const float* __restrict__ bias, const float* __restrict__ gamma,
                  const float* __restrict__ beta, const float* __restrict__ mean,
                  const float* __restrict__ var, char* __restrict__ outBuf)
{
    constexpr int CIN = 2;
    __shared__ float wlds[CIN * 32 * 9];
    const int t = blockIdx.x, b = blockIdx.y;
    const int tid = threadIdx.x;
    const int cg = tid >> 5;
    const int f0 = (tid & 31) * 8;

    for (int idx = tid; idx < CIN * 32 * 9; idx += 256) {
        int ci = idx / 288, r = idx - ci * 288;
        int cgi = r / 36, r2 = r - cgi * 36;
        int j = r2 / 9, k = r2 - j * 9;
        int co = 2 * cgi + (j & 1) + (j >> 1) * 16;
        wlds[idx] = w[(co * CIN + ci) * 9 + k];
    }
    __syncthreads();

    float bns[4], bno[4], acc[4][8];
    #pragma unroll
    for (int j = 0; j < 4; j++) {
        int c = 2 * cg + (j & 1) + (j >> 1) * 16;
        float s = gamma[c] * rsqrtf(var[c] + 1e-5f);
        bns[j] = s; bno[j] = beta[c] - mean[c] * s;
        float bi = bias[c];
        #pragma unroll
        for (int q = 0; q < 8; q++) acc[j][q] = bi;
    }

    for (int ci = 0; ci < CIN; ci++) {
        float wr[36];
        const float4* wv4 = (const float4*)(wlds + ci * 288 + cg * 36);
        #pragma unroll
        for (int v = 0; v < 9; v++) ((float4*)wr)[v] = wv4[v];
        #pragma unroll
        for (int dt = 0; dt < 3; dt++) {
            int t_in = t + dt - 1;
            bool trow = (t_in >= 0) && (t_in < Tt);
            const float* rowp = x + ((size_t)(b * CIN + ci) * Tt + (trow ? t_in : 0)) * Ff;
            float buf[16];
            #pragma unroll
            for (int v = 0; v < 4; v++) {
                int fb = f0 - 4 + v * 4;
                float4 val = make_float4(0.f, 0.f, 0.f, 0.f);
                if (trow && fb >= 0 && fb <= Ff - 4) val = *(const float4*)(rowp + fb);
                buf[v*4+0] = val.x; buf[v*4+1] = val.y; buf[v*4+2] = val.z; buf[v*4+3] = val.w;
            }
            #pragma unroll
            for (int kf = 0; kf < 3; kf++)
                #pragma unroll
                for (int j = 0; j < 4; j++) {
                    float wj = wr[j * 9 + dt * 3 + kf];
                    #pragma unroll
                    for (int q = 0; q < 8; q++)
                        acc[j][q] = fmaf(buf[4 + q + kf - 1], wj, acc[j][q]);
                }
        }
    }

    float res[2][8];
    #pragma unroll
    for (int jj = 0; jj < 2; jj++)
        #pragma unroll
        for (int q = 0; q < 8; q++) {
            float a = acc[jj][q] * bns[jj] + bno[jj];
            float g = acc[jj + 2][q] * bns[jj + 2] + bno[jj + 2];
            res[jj][q] = fast_tanh(a) * fast_sigmoid(g);
        }
    // write 2 channels (2cg, 2cg+1) hi+lo into swizzled cells
    #pragma unroll
    for (int q = 0; q < 8; q++) {
        int fp = f0 + q + 8;
        char* cell = outBuf + ((size_t)(b * TROW + t + 8) * FROW + fp) * CELL;
        unsigned short h0 = bf16_rne(res[0][q]), h1 = bf16_rne(res[1][q]);
        unsigned short l0 = bf16_rne(res[0][q] - bf16_to_f(h0));
        unsigned short l1 = bf16_rne(res[1][q] - bf16_to_f(h1));
        unsigned hw = (unsigned)h0 | ((unsigned)h1 << 16);
        unsigned lw = (unsigned)l0 | ((unsigned)l1 << 16);
        int inner = (4 * cg) & 15;
        int sub_hi = (cg >> 2) ^ (fp & 3);
        int sub_lo = (2 + (cg >> 2)) ^ (fp & 3);
        *(unsigned*)(cell + sub_hi * 16 + inner) = hw;
        *(unsigned*)(cell + sub_lo * 16 + inner) = lw;
    }
}

// ---------- convs 2-4: MFMA implicit GEMM, bf16 hi/lo 3-pass ----------
template<int DIL, int WRITE_F32>
__global__ __launch_bounds__(256, 2)
void gate_mfma(const char* __restrict__ actIn, const char* __restrict__ wpre,
               const float* __restrict__ bpre, char* __restrict__ outBuf)
{
    __shared__ char actL[3 * ROWBYTES];    // 52224 B
    const int t = blockIdx.x, b = blockIdx.y;
    const int tid = threadIdx.x;
    const int wv = tid >> 6, lane = tid & 63;
    const int n = lane & 15, q = lane >> 4;

    // A-fragments (weights) from global (L2-hot), registers
    short8 aH[5][2], aL[5][2];
    #pragma unroll
    for (int ks = 0; ks < 5; ks++)
        #pragma unroll
        for (int ct = 0; ct < 2; ct++) {
            int co = ct * 16 + n;
            int sub = q ^ (co & 3);
            aH[ks][ct] = *(const short8*)(wpre + (size_t)((0 * 5 + ks) * 32 + co) * 64 + sub * 16);
            aL[ks][ct] = *(const short8*)(wpre + (size_t)((5 + ks) * 32 + co) * 64 + sub * 16);
        }

    // stage 3 act rows (t-d, t, t+d), contiguous 1088 chunks each
    #pragma unroll
    for (int r = 0; r < 3; r++) {
        int tp = t + 8 + (r - 1) * DIL;
        const char* src = actIn + ((size_t)(b * TROW + tp) * FROW) * CELL;
        char* dst = actL + r * ROWBYTES;
        #pragma unroll
        for (int i = 0; i < 4; i++)
            GLOAD_LDS(src + (i * 256 + tid) * 16, dst + (i * 256 + wv * 64) * 16);
        if (tid < 64)
            GLOAD_LDS(src + (1024 + lane) * 16, dst + 1024 * 16);
    }
    __syncthreads();

    const int fb = wv * 64;
    f32x4 acc[4][2] = {};

    #pragma unroll
    for (int ks = 0; ks < 5; ks++) {
        const int tapA = 2 * ks;
        const int tapB = (2 * ks + 1 > 8) ? 8 : 2 * ks + 1;
        const int rowA = tapA / 3, dfA = (tapA % 3 - 1) * DIL;
        const int rowB = tapB / 3, dfB = (tapB % 3 - 1) * DIL;
        int tapSel = q >> 1;
        int row = tapSel ? rowB : rowA;
        int df  = tapSel ? dfB : dfA;
        int cih = q & 1;
        const char* rbase = actL + row * ROWBYTES;
        #pragma unroll
        for (int nt = 0; nt < 4; nt++) {
            int fp = fb + nt * 16 + n + 8 + df;
            const char* cell = rbase + fp * CELL;
            short8 bH = *(const short8*)(cell + ((cih) ^ (fp & 3)) * 16);
            short8 bL = *(const short8*)(cell + ((2 + cih) ^ (fp & 3)) * 16);
            #pragma unroll
            for (int ct = 0; ct < 2; ct++) {
                acc[nt][ct] = mfma_bf16(aH[ks][ct], bH, acc[nt][ct]);
                acc[nt][ct] = mfma_bf16(aL[ks][ct], bH, acc[nt][ct]);
                acc[nt][ct] = mfma_bf16(aH[ks][ct], bL, acc[nt][ct]);
            }
        }
    }

    // epilogue: GLU, then store
    float4 bA = *(const float4*)(bpre + q * 4);
    float4 bG = *(const float4*)(bpre + 16 + q * 4);
    #pragma unroll
    for (int nt = 0; nt < 4; nt++) {
        float r[4];
        r[0] = fast_tanh(acc[nt][0].x + bA.x) * fast_sigmoid(acc[nt][1].x + bG.x);
        r[1] = fast_tanh(acc[nt][0].y + bA.y) * fast_sigmoid(acc[nt][1].y + bG.y);
        r[2] = fast_tanh(acc[nt][0].z + bA.z) * fast_sigmoid(acc[nt][1].z + bG.z);
        r[3] = fast_tanh(acc[nt][0].w + bA.w) * fast_sigmoid(acc[nt][1].w + bG.w);
        int f = fb + nt * 16 + n;
        if (WRITE_F32) {
            float* gp = (float*)outBuf;
            #pragma unroll
            for (int j = 0; j < 4; j++)
                gp[((size_t)(b * 16 + q * 4 + j) * Tt + t) * Ff + f] = r[j];
        } else {
            int fp = f + 8;
            char* cell = outBuf + ((size_t)(b * TROW + t + 8) * FROW + fp) * CELL;
            unsigned short h[4], l[4];
            #pragma unroll
            for (int j = 0; j < 4; j++) {
                h[j] = bf16_rne(r[j]);
                l[j] = bf16_rne(r[j] - bf16_to_f(h[j]));
            }
            uint2 hw, lw;
            hw.x = (unsigned)h[0] | ((unsigned)h[1] << 16);
            hw.y = (unsigned)h[2] | ((unsigned)h[3] << 16);
            lw.x = (unsigned)l[0] | ((unsigned)l[1] << 16);
            lw.y = (unsigned)l[2] | ((unsigned)l[3] << 16);
            int inner = (q & 1) * 8;
            *(uint2*)(cell + (((q >> 1) ^ (fp & 3)) * 16) + inner) = hw;
            *(uint2*)(cell + (((2 + (q >> 1)) ^ (fp & 3)) * 16) + inner) = lw;
        }
    }
}

// ---------- grouped GRU (H=2) + fused out_w partial dot ----------
// LDS-DMA staged: 32-step chunks via global_load_lds (no dest VGPR -> compiler
// can't throttle MLP), ping-pong LDS, explicit s_waitcnt vmcnt(16) so the
// next chunk's 16 staging ops stay in flight during compute.
// part layout: [b][g][fsl(4)][tpair(256)][lane(64)][2]
__global__ __launch_bounds__(64)
void gru_kernel(const float* __restrict__ xin, const float* __restrict__ wih,
                const float* __restrict__ whh, const float* __restrict__ bih,
                const float* __restrict__ bhh, const float* __restrict__ out_w,
                float* __restrict__ part)
{
    __shared__ float ldsF[2 * 4096];   // 2 x 16 KB ping-pong
    const int lane = threadIdx.x;
    const int fsl = blockIdx.x & 3;
    const int g = (blockIdx.x >> 2) & 7;
    const int b = blockIdx.x >> 5;

    float Wih[6][2], Whh[6][2], Bih[6], Bhh[6];
    #pragma unroll
    for (int k = 0; k < 6; k++) {
        Wih[k][0] = wih[g * 12 + k * 2 + 0];
        Wih[k][1] = wih[g * 12 + k * 2 + 1];
        Whh[k][0] = whh[g * 12 + k * 2 + 0];
        Whh[k][1] = whh[g * 12 + k * 2 + 1];
        Bih[k] = bih[g * 6 + k];
        Bhh[k] = bhh[g * 6 + k];
    }
    const float ow0 = out_w[2 * g], ow1 = out_w[2 * g + 1];

    // staging source: lane sub covers 16B of row (c, t0+2j+tp), f-slice fsl
    const int sub = lane & 15, cch = (lane >> 4) & 1, tpr = lane >> 5;
    const float* gsrc = xin + ((size_t)(b * Cc + 2 * g + cch) * Tt + tpr) * Ff + fsl * 64 + sub * 4;

    float* poBase = part + ((size_t)((b * 8 + g) * 4 + fsl)) * 32768;

    #define STAGE(bsel, t0s)                                                  \
    {                                                                         \
        char* ldst = (char*)(ldsF + (bsel) * 4096);                           \
        const float* gs = gsrc + (size_t)(t0s) * Ff;                          \
        _Pragma("unroll")                                                     \
        for (int j = 0; j < 16; j++)                                          \
            GLOAD_LDS(gs + 2 * j * Ff, ldst + j * 1024);                      \
    }

    float h0 = 0.f, h1 = 0.f;
    STAGE(0, 0);
    int buf = 0;
    for (int t0 = 0; t0 < Tt; t0 += 32) {
        if (t0 + 32 < Tt) STAGE(buf ^ 1, t0 + 32);
        // vmcnt(16): wait for current chunk (+older stores), keep next chunk in flight
        __builtin_amdgcn_s_waitcnt(0x4F70);
        float2 outR[16];
        #pragma unroll
        for (int tt = 0; tt < 32; tt++) {
            const float* cell = ldsF + buf * 4096 + (tt >> 1) * 256 + (tt & 1) * 128;
            float x0 = cell[lane];
            float x1 = cell[64 + lane];
            float gi[6], gh[6];
            #pragma unroll
            for (int k = 0; k < 6; k++) {
                gi[k] = fmaf(Wih[k][0], x0, fmaf(Wih[k][1], x1, Bih[k]));
                gh[k] = fmaf(Whh[k][0], h0, fmaf(Whh[k][1], h1, Bhh[k]));
            }
            float r0 = fast_sigmoid(gi[0] + gh[0]);
            float r1 = fast_sigmoid(gi[1] + gh[1]);
            float z0 = fast_sigmoid(gi[2] + gh[2]);
            float z1 = fast_sigmoid(gi[3] + gh[3]);
            float n0 = fast_tanh(gi[4] + r0 * gh[4]);
            float n1 = fast_tanh(gi[5] + r1 * gh[5]);
            h0 = (1.0f - z0) * n0 + z0 * h0;
            h1 = (1.0f - z1) * n1 + z1 * h1;
            float o = fmaf(h0, ow0, h1 * ow1);
            if (tt & 1) outR[tt >> 1].y = o; else outR[tt >> 1].x = o;
        }
        #pragma unroll
        for (int j = 0; j < 16; j++)
            *(float2*)(poBase + ((t0 >> 1) + j) * 128 + lane * 2) = outR[j];
        buf ^= 1;
    }
    #undef STAGE
}

// sum 8 group partials (new part layout) + out_b -> (B,1,T,F)
__global__ __launch_bounds__(256)
void out_kernel(const float* __restrict__ part, const float* __restrict__ out_b,
                float* __restrict__ out)
{
    int idx = blockIdx.x * 256 + threadIdx.x;    // 524288 total: [b][tpair][f]
    int f = idx & 255;
    int tp = (idx >> 8) & 255;
    int b = idx >> 16;
    int fsl = f >> 6, ln = f & 63;
    const float* base = part + ((size_t)(b * 8) * 4 + fsl) * 32768 + tp * 128 + ln * 2;
    float ob = out_b[0];
    float s0 = ob, s1 = ob;
    #pragma unroll
    for (int g = 0; g < 8; g++) {
        float2 v = *(const float2*)(base + (size_t)g * 131072);
        s0 += v.x; s1 += v.y;
    }
    float* op = out + ((size_t)b * Tt + 2 * tp) * Ff + f;
    op[0] = s0;
    op[Ff] = s1;
}

extern "C" void kernel_launch(void* const* d_in, const int* in_sizes, int n_in,
                              void* d_out, int out_size, void* d_ws, size_t ws_size,
                              hipStream_t stream) {
    char* bufA = (char*)d_ws;
    char* bufB = bufA + BUFBYTES;
    char* wpre = bufB + BUFBYTES;
    float* bpre = (float*)(wpre + 3 * 20480);

    padzero<<<784, 256, 0, stream>>>(bufA, bufB);
    wsetup<<<1, 256, 0, stream>>>((const float*)d_in[7],  (const float*)d_in[8],  (const float*)d_in[9],
                                  (const float*)d_in[10], (const float*)d_in[11], (const float*)d_in[12],
                                  wpre, bpre);
    wsetup<<<1, 256, 0, stream>>>((const float*)d_in[13], (const float*)d_in[14], (const float*)d_in[15],
                                  (const float*)d_in[16], (const float*)d_in[17], (const float*)d_in[18],
                                  wpre + 20480, bpre + 32);
    wsetup<<<1, 256, 0, stream>>>((const float*)d_in[19], (const float*)d_in[20], (const float*)d_in[21],
                                  (const float*)d_in[22], (const float*)d_in[23], (const float*)d_in[24],
                                  wpre + 40960, bpre + 64);

    dim3 grid(Tt, Bb), blk(256);
    gate1_kernel<<<grid, blk, 0, stream>>>(
        (const float*)d_in[0], (const float*)d_in[1], (const float*)d_in[2], (const float*)d_in[3],
        (const float*)d_in[4], (const float*)d_in[5], (const float*)d_in[6], bufA);

    gate_mfma<2, 0><<<grid, blk, 0, stream>>>(bufA, wpre,        bpre,      bufB);
    gate_mfma<4, 0><<<grid, blk, 0, stream>>>(bufB, wpre + 20480, bpre + 32, bufA);
    gate_mfma<8, 1><<<grid, blk, 0, stream>>>(bufA, wpre + 40960, bpre + 64, bufB);

    // GRU reads fp32 gruIn (bufB), writes partials into bufA
    gru_kernel<<<Bb * 8 * 4, 64, 0, stream>>>(
        (const float*)bufB, (const float*)d_in[25], (const float*)d_in[26], (const float*)d_in[27],
        (const float*)d_in[28], (const float*)d_in[29], (float*)bufA);

    out_kernel<<<2048, 256, 0, stream>>>(
        (const float*)bufA, (const float*)d_in[30], (float*)d_out);
}

// Round 6
// 377.071 us; speedup vs baseline: 1.5533x; 1.1805x over previous
//
#include <hip/hip_runtime.h>
#include <math.h>

#define Bb 8
#define Tt 512
#define Ff 256
#define Cc 16
#define TF (Tt*Ff)
#define TROW 528
#define FROW 272
#define CELL 64
#define ROWBYTES (FROW*CELL)                       // 17408
#define BUFBYTES ((size_t)Bb*TROW*FROW*CELL)       // 73,531,392

typedef __attribute__((ext_vector_type(8))) short short8;
typedef __attribute__((ext_vector_type(4))) float f32x4;

typedef const __attribute__((address_space(1))) void* gas1_t;
typedef __attribute__((address_space(3))) void* las3_t;
#define GLOAD_LDS(g, l) __builtin_amdgcn_global_load_lds((gas1_t)(const void*)(g), (las3_t)(void*)(l), 16, 0, 0)

__device__ __forceinline__ float fast_sigmoid(float x) {
    return __builtin_amdgcn_rcpf(1.0f + __expf(-x));
}
__device__ __forceinline__ float fast_tanh(float x) {
    return 1.0f - 2.0f * __builtin_amdgcn_rcpf(__expf(2.0f * x) + 1.0f);
}

__device__ __forceinline__ unsigned short bf16_rne(float x) {
    unsigned u = __float_as_uint(x);
    u += 0x7fffu + ((u >> 16) & 1u);
    return (unsigned short)(u >> 16);
}
__device__ __forceinline__ float bf16_to_f(unsigned short h) {
    return __uint_as_float(((unsigned)h) << 16);
}
__device__ __forceinline__ f32x4 mfma_bf16(short8 a, short8 b, f32x4 c) {
    return __builtin_amdgcn_mfma_f32_16x16x32_bf16(a, b, c, 0, 0, 0);
}

// ---------- merged setup: blocks 0-2 = BN-fold+split weights for convs 2-4;
// blocks 3..786 = zero halo pads of bufA/bufB ----------
__global__ __launch_bounds__(256)
void setup_all(const float* __restrict__ w2, const float* __restrict__ b2, const float* __restrict__ gm2,
               const float* __restrict__ bt2, const float* __restrict__ mn2, const float* __restrict__ vr2,
               const float* __restrict__ w3, const float* __restrict__ b3, const float* __restrict__ gm3,
               const float* __restrict__ bt3, const float* __restrict__ mn3, const float* __restrict__ vr3,
               const float* __restrict__ w4, const float* __restrict__ b4, const float* __restrict__ gm4,
               const float* __restrict__ bt4, const float* __restrict__ mn4, const float* __restrict__ vr4,
               char* __restrict__ bufA, char* __restrict__ bufB,
               char* __restrict__ wpreAll, float* __restrict__ bpreAll)
{
    const int blk = blockIdx.x;
    const int tid = threadIdx.x;
    if (blk < 3) {
        const float *w, *bias, *gamma, *beta, *mean, *var;
        if (blk == 0)      { w = w2; bias = b2; gamma = gm2; beta = bt2; mean = mn2; var = vr2; }
        else if (blk == 1) { w = w3; bias = b3; gamma = gm3; beta = bt3; mean = mn3; var = vr3; }
        else               { w = w4; bias = b4; gamma = gm4; beta = bt4; mean = mn4; var = vr4; }
        char* wpre = wpreAll + blk * 20480;
        float* bpre = bpreAll + blk * 32;
        if (tid < 32) {
            float s = gamma[tid] * rsqrtf(var[tid] + 1e-5f);
            bpre[tid] = (bias[tid] - mean[tid]) * s + beta[tid];
        }
        for (int i = tid; i < 4608; i += 256) {
            int co = i / 144, r = i - co * 144;
            int ci = r / 9, tap = r - ci * 9;
            float s = gamma[co] * rsqrtf(var[co] + 1e-5f);
            float wv = w[(co * 16 + ci) * 9 + tap] * s;
            unsigned short hi = bf16_rne(wv);
            unsigned short lo = bf16_rne(wv - bf16_to_f(hi));
            int ks = tap >> 1, tp = tap & 1;
            int kl = tp * 16 + ci;
            int qq = kl >> 3, jj = kl & 7;
            int sub = qq ^ (co & 3);
            *(unsigned short*)(wpre + ((0 * 5 + ks) * 32 + co) * 64 + sub * 16 + jj * 2) = hi;
            *(unsigned short*)(wpre + ((1 * 5 + ks) * 32 + co) * 64 + sub * 16 + jj * 2) = lo;
        }
        for (int i = tid; i < 1024; i += 256) {
            int p = i >> 9, rem = i & 511;
            int co = rem >> 4, kl = 16 + (rem & 15);
            int qq = kl >> 3, jj = kl & 7;
            int sub = qq ^ (co & 3);
            *(unsigned short*)(wpre + ((p * 5 + 4) * 32 + co) * 64 + sub * 16 + jj * 2) = 0;
        }
    } else {
        int idx = (blk - 3) * 256 + tid;      // 200704 cells total
        int which = idx >= 100352;
        int r0 = which ? idx - 100352 : idx;
        int b = r0 / 12544, c = r0 - b * 12544;
        int tp, fp;
        if (c < 4352) { int row = c / 272; fp = c - row * 272; tp = row < 8 ? row : 512 + row; }
        else { int c2 = c - 4352; tp = 8 + (c2 >> 4); int fi = c2 & 15; fp = fi < 8 ? fi : 256 + fi; }
        char* base = (which ? bufB : bufA) + ((size_t)(b * TROW + tp) * FROW + fp) * CELL;
        float4 z = make_float4(0.f, 0.f, 0.f, 0.f);
        float4* p = (float4*)base;
        p[0] = z; p[1] = z; p[2] = z; p[3] = z;
    }
}

// ---------- conv1 (CIN=2, dil=1): tiled, LDS-staged, whole-chunk stores ----------
// block = 4t x 64f tile; thread = (fl, tr in {0,1}, h in {0,1}):
//   computes 2 pixels (t0+2tr, t0+2tr+1) x 16 channels {h*8..+7, 16+h*8..+7}
__global__ __launch_bounds__(256)
void gate1_kernel(const float* __restrict__ x, const float* __restrict__ w,
                  const float* __restrict__ bias, const float* __restrict__ gamma,
                  const float* __restrict__ beta, const float* __restrict__ mean,
                  const float* __restrict__ var, char* __restrict__ outBuf)
{
    __shared__ float xs[2][6][66];     // [ci][t0-1..t0+4][f0-1..f0+64]
    __shared__ float wl[18 * 32];      // [(ci*9+tap)][co]
    __shared__ float bnsL[32], bnoL[32];
    const int f0 = blockIdx.x * 64;
    const int t0 = blockIdx.y * 4;
    const int b  = blockIdx.z;
    const int tid = threadIdx.x;
    const int fl = tid & 63;
    const int tr = (tid >> 6) & 1;
    const int h  = tid >> 7;

    if (tid < 32) {
        float s = gamma[tid] * rsqrtf(var[tid] + 1e-5f);
        bnsL[tid] = s;
        bnoL[tid] = (bias[tid] - mean[tid]) * s + beta[tid];
    }
    for (int i = tid; i < 576; i += 256) {
        int co = i & 31, rest = i >> 5;        // rest = ci*9+tap
        int ci = rest / 9, tap = rest - ci * 9;
        wl[rest * 32 + co] = w[(co * 2 + ci) * 9 + tap];
    }
    for (int i = tid; i < 792; i += 256) {
        int ci = i / 396, r = i - ci * 396;
        int row = r / 66, col = r - row * 66;
        int t_in = t0 + row - 1, f_in = f0 + col - 1;
        float v = 0.f;
        if (t_in >= 0 && t_in < Tt && f_in >= 0 && f_in < Ff)
            v = x[((size_t)(b * 2 + ci) * Tt + t_in) * Ff + f_in];
        xs[ci][row][col] = v;
    }
    __syncthreads();

    float acc[2][16];
    #pragma unroll
    for (int q = 0; q < 2; q++)
        #pragma unroll
        for (int j = 0; j < 16; j++) acc[q][j] = 0.f;

    #pragma unroll
    for (int ci = 0; ci < 2; ci++) {
        // 4 window rows x 3 cols per ci (shared between the 2 pixels)
        float win[4][3];
        #pragma unroll
        for (int r = 0; r < 4; r++)
            #pragma unroll
            for (int c = 0; c < 3; c++)
                win[r][c] = xs[ci][2 * tr + r][fl + c];
        #pragma unroll
        for (int dt = 0; dt < 3; dt++)
            #pragma unroll
            for (int kf = 0; kf < 3; kf++) {
                float xv0 = win[dt][kf];
                float xv1 = win[dt + 1][kf];
                const float* wrow = wl + (ci * 9 + dt * 3 + kf) * 32 + h * 8;
                float wv[16];
                *(float4*)(wv)      = *(const float4*)(wrow);
                *(float4*)(wv + 4)  = *(const float4*)(wrow + 4);
                *(float4*)(wv + 8)  = *(const float4*)(wrow + 16);
                *(float4*)(wv + 12) = *(const float4*)(wrow + 20);
                #pragma unroll
                for (int j = 0; j < 16; j++) {
                    acc[0][j] = fmaf(xv0, wv[j], acc[0][j]);
                    acc[1][j] = fmaf(xv1, wv[j], acc[1][j]);
                }
            }
    }

    // epilogue: BN + GLU, pack whole 16B chunks, 2 stores per pixel
    #pragma unroll
    for (int q = 0; q < 2; q++) {
        int t = t0 + 2 * tr + q;
        int fp = f0 + fl + 8;
        int sw = fp & 3;
        char* cell = outBuf + ((size_t)(b * TROW + t + 8) * FROW + fp) * CELL;
        unsigned short hi[8], lo[8];
        #pragma unroll
        for (int j = 0; j < 8; j++) {
            int ca = h * 8 + j, cg = 16 + h * 8 + j;
            float av = acc[q][j]     * bnsL[ca] + bnoL[ca];
            float gv = acc[q][8 + j] * bnsL[cg] + bnoL[cg];
            float r = fast_tanh(av) * fast_sigmoid(gv);
            hi[j] = bf16_rne(r);
            lo[j] = bf16_rne(r - bf16_to_f(hi[j]));
        }
        uint4 H, L;
        H.x = (unsigned)hi[0] | ((unsigned)hi[1] << 16);
        H.y = (unsigned)hi[2] | ((unsigned)hi[3] << 16);
        H.z = (unsigned)hi[4] | ((unsigned)hi[5] << 16);
        H.w = (unsigned)hi[6] | ((unsigned)hi[7] << 16);
        L.x = (unsigned)lo[0] | ((unsigned)lo[1] << 16);
        L.y = (unsigned)lo[2] | ((unsigned)lo[3] << 16);
        L.z = (unsigned)lo[4] | ((unsigned)lo[5] << 16);
        L.w = (unsigned)lo[6] | ((unsigned)lo[7] << 16);
        *(uint4*)(cell + ((h)     ^ sw) * 16) = H;
        *(uint4*)(cell + ((2 + h) ^ sw) * 16) = L;
    }
}

// ---------- convs 2-4: MFMA implicit GEMM, bf16 hi/lo 3-pass ----------
template<int DIL, int WRITE_F32>
__global__ __launch_bounds__(256, 2)
void gate_mfma(const char* __restrict__ actIn, const char* __restrict__ wpre,
               const float* __restrict__ bpre, char* __restrict__ outBuf)
{
    __shared__ char actL[3 * ROWBYTES];    // 52224 B
    const int t = blockIdx.x, b = blockIdx.y;
    const int tid = threadIdx.x;
    const int wv = tid >> 6, lane = tid & 63;
    const int n = lane & 15, q = lane >> 4;

    // A-fragments (weights) from global (L2-hot), registers
    short8 aH[5][2], aL[5][2];
    #pragma unroll
    for (int ks = 0; ks < 5; ks++)
        #pragma unroll
        for (int ct = 0; ct < 2; ct++) {
            int co = ct * 16 + n;
            int sub = q ^ (co & 3);
            aH[ks][ct] = *(const short8*)(wpre + (size_t)((0 * 5 + ks) * 32 + co) * 64 + sub * 16);
            aL[ks][ct] = *(const short8*)(wpre + (size_t)((5 + ks) * 32 + co) * 64 + sub * 16);
        }

    // stage 3 act rows (t-d, t, t+d), contiguous 1088 chunks each
    #pragma unroll
    for (int r = 0; r < 3; r++) {
        int tp = t + 8 + (r - 1) * DIL;
        const char* src = actIn + ((size_t)(b * TROW + tp) * FROW) * CELL;
        char* dst = actL + r * ROWBYTES;
        #pragma unroll
        for (int i = 0; i < 4; i++)
            GLOAD_LDS(src + (i * 256 + tid) * 16, dst + (i * 256 + wv * 64) * 16);
        if (tid < 64)
            GLOAD_LDS(src + (1024 + lane) * 16, dst + 1024 * 16);
    }
    __syncthreads();

    const int fb = wv * 64;
    f32x4 acc[4][2] = {};

    #pragma unroll
    for (int ks = 0; ks < 5; ks++) {
        const int tapA = 2 * ks;
        const int tapB = (2 * ks + 1 > 8) ? 8 : 2 * ks + 1;
        const int rowA = tapA / 3, dfA = (tapA % 3 - 1) * DIL;
        const int rowB = tapB / 3, dfB = (tapB % 3 - 1) * DIL;
        int tapSel = q >> 1;
        int row = tapSel ? rowB : rowA;
        int df  = tapSel ? dfB : dfA;
        int cih = q & 1;
        const char* rbase = actL + row * ROWBYTES;
        #pragma unroll
        for (int nt = 0; nt < 4; nt++) {
            int fp = fb + nt * 16 + n + 8 + df;
            const char* cell = rbase + fp * CELL;
            short8 bH = *(const short8*)(cell + ((cih) ^ (fp & 3)) * 16);
            short8 bL = *(const short8*)(cell + ((2 + cih) ^ (fp & 3)) * 16);
            #pragma unroll
            for (int ct = 0; ct < 2; ct++) {
                acc[nt][ct] = mfma_bf16(aH[ks][ct], bH, acc[nt][ct]);
                acc[nt][ct] = mfma_bf16(aL[ks][ct], bH, acc[nt][ct]);
                acc[nt][ct] = mfma_bf16(aH[ks][ct], bL, acc[nt][ct]);
            }
        }
    }

    // epilogue: GLU, then store
    float4 bA = *(const float4*)(bpre + q * 4);
    float4 bG = *(const float4*)(bpre + 16 + q * 4);
    #pragma unroll
    for (int nt = 0; nt < 4; nt++) {
        float r[4];
        r[0] = fast_tanh(acc[nt][0].x + bA.x) * fast_sigmoid(acc[nt][1].x + bG.x);
        r[1] = fast_tanh(acc[nt][0].y + bA.y) * fast_sigmoid(acc[nt][1].y + bG.y);
        r[2] = fast_tanh(acc[nt][0].z + bA.z) * fast_sigmoid(acc[nt][1].z + bG.z);
        r[3] = fast_tanh(acc[nt][0].w + bA.w) * fast_sigmoid(acc[nt][1].w + bG.w);
        int f = fb + nt * 16 + n;
        if (WRITE_F32) {
            float* gp = (float*)outBuf;
            #pragma unroll
            for (int j = 0; j < 4; j++)
                gp[((size_t)(b * 16 + q * 4 + j) * Tt + t) * Ff + f] = r[j];
        } else {
            int fp = f + 8;
            char* cell = outBuf + ((size_t)(b * TROW + t + 8) * FROW + fp) * CELL;
            unsigned short h[4], l[4];
            #pragma unroll
            for (int j = 0; j < 4; j++) {
                h[j] = bf16_rne(r[j]);
                l[j] = bf16_rne(r[j] - bf16_to_f(h[j]));
            }
            uint2 hw, lw;
            hw.x = (unsigned)h[0] | ((unsigned)h[1] << 16);
            hw.y = (unsigned)h[2] | ((unsigned)h[3] << 16);
            lw.x = (unsigned)l[0] | ((unsigned)l[1] << 16);
            lw.y = (unsigned)l[2] | ((unsigned)l[3] << 16);
            int inner = (q & 1) * 8;
            *(uint2*)(cell + (((q >> 1) ^ (fp & 3)) * 16) + inner) = hw;
            *(uint2*)(cell + (((2 + (q >> 1)) ^ (fp & 3)) * 16) + inner) = lw;
        }
    }
}

// ---------- grouped GRU (H=2) + fused out_w partial dot ----------
// LDS-DMA staged: 32-step chunks via global_load_lds, ping-pong LDS,
// explicit s_waitcnt vmcnt(16) keeps next chunk's staging in flight.
// part layout: [b][g][fsl(4)][tpair(256)][lane(64)][2]
__global__ __launch_bounds__(64)
void gru_kernel(const float* __restrict__ xin, const float* __restrict__ wih,
                const float* __restrict__ whh, const float* __restrict__ bih,
                const float* __restrict__ bhh, const float* __restrict__ out_w,
                float* __restrict__ part)
{
    __shared__ float ldsF[2 * 4096];   // 2 x 16 KB ping-pong
    const int lane = threadIdx.x;
    const int fsl = blockIdx.x & 3;
    const int g = (blockIdx.x >> 2) & 7;
    const int b = blockIdx.x >> 5;

    float Wih[6][2], Whh[6][2], Bih[6], Bhh[6];
    #pragma unroll
    for (int k = 0; k < 6; k++) {
        Wih[k][0] = wih[g * 12 + k * 2 + 0];
        Wih[k][1] = wih[g * 12 + k * 2 + 1];
        Whh[k][0] = whh[g * 12 + k * 2 + 0];
        Whh[k][1] = whh[g * 12 + k * 2 + 1];
        Bih[k] = bih[g * 6 + k];
        Bhh[k] = bhh[g * 6 + k];
    }
    const float ow0 = out_w[2 * g], ow1 = out_w[2 * g + 1];

    const int sub = lane & 15, cch = (lane >> 4) & 1, tpr = lane >> 5;
    const float* gsrc = xin + ((size_t)(b * Cc + 2 * g + cch) * Tt + tpr) * Ff + fsl * 64 + sub * 4;

    float* poBase = part + ((size_t)((b * 8 + g) * 4 + fsl)) * 32768;

    #define STAGE(bsel, t0s)                                                  \
    {                                                                         \
        char* ldst = (char*)(ldsF + (bsel) * 4096);                           \
        const float* gs = gsrc + (size_t)(t0s) * Ff;                          \
        _Pragma("unroll")                                                     \
        for (int j = 0; j < 16; j++)                                          \
            GLOAD_LDS(gs + 2 * j * Ff, ldst + j * 1024);                      \
    }

    float h0 = 0.f, h1 = 0.f;
    STAGE(0, 0);
    int buf = 0;
    for (int t0 = 0; t0 < Tt; t0 += 32) {
        if (t0 + 32 < Tt) STAGE(buf ^ 1, t0 + 32);
        __builtin_amdgcn_s_waitcnt(0x4F70);   // vmcnt(16)
        float2 outR[16];
        #pragma unroll
        for (int tt = 0; tt < 32; tt++) {
            const float* cell = ldsF + buf * 4096 + (tt >> 1) * 256 + (tt & 1) * 128;
            float x0 = cell[lane];
            float x1 = cell[64 + lane];
            float gi[6], gh[6];
            #pragma unroll
            for (int k = 0; k < 6; k++) {
                gi[k] = fmaf(Wih[k][0], x0, fmaf(Wih[k][1], x1, Bih[k]));
                gh[k] = fmaf(Whh[k][0], h0, fmaf(Whh[k][1], h1, Bhh[k]));
            }
            float r0 = fast_sigmoid(gi[0] + gh[0]);
            float r1 = fast_sigmoid(gi[1] + gh[1]);
            float z0 = fast_sigmoid(gi[2] + gh[2]);
            float z1 = fast_sigmoid(gi[3] + gh[3]);
            float n0 = fast_tanh(gi[4] + r0 * gh[4]);
            float n1 = fast_tanh(gi[5] + r1 * gh[5]);
            h0 = (1.0f - z0) * n0 + z0 * h0;
            h1 = (1.0f - z1) * n1 + z1 * h1;
            float o = fmaf(h0, ow0, h1 * ow1);
            if (tt & 1) outR[tt >> 1].y = o; else outR[tt >> 1].x = o;
        }
        #pragma unroll
        for (int j = 0; j < 16; j++)
            *(float2*)(poBase + ((t0 >> 1) + j) * 128 + lane * 2) = outR[j];
        buf ^= 1;
    }
    #undef STAGE
}

// sum 8 group partials (part layout) + out_b -> (B,1,T,F)
__global__ __launch_bounds__(256)
void out_kernel(const float* __restrict__ part, const float* __restrict__ out_b,
                float* __restrict__ out)
{
    int idx = blockIdx.x * 256 + threadIdx.x;    // 524288 total: [b][tpair][f]
    int f = idx & 255;
    int tp = (idx >> 8) & 255;
    int b = idx >> 16;
    int fsl = f >> 6, ln = f & 63;
    const float* base = part + ((size_t)(b * 8) * 4 + fsl) * 32768 + tp * 128 + ln * 2;
    float ob = out_b[0];
    float s0 = ob, s1 = ob;
    #pragma unroll
    for (int g = 0; g < 8; g++) {
        float2 v = *(const float2*)(base + (size_t)g * 131072);
        s0 += v.x; s1 += v.y;
    }
    float* op = out + ((size_t)b * Tt + 2 * tp) * Ff + f;
    op[0] = s0;
    op[Ff] = s1;
}

extern "C" void kernel_launch(void* const* d_in, const int* in_sizes, int n_in,
                              void* d_out, int out_size, void* d_ws, size_t ws_size,
                              hipStream_t stream) {
    char* bufA = (char*)d_ws;
    char* bufB = bufA + BUFBYTES;
    char* wpre = bufB + BUFBYTES;
    float* bpre = (float*)(wpre + 3 * 20480);

    setup_all<<<787, 256, 0, stream>>>(
        (const float*)d_in[7],  (const float*)d_in[8],  (const float*)d_in[9],
        (const float*)d_in[10], (const float*)d_in[11], (const float*)d_in[12],
        (const float*)d_in[13], (const float*)d_in[14], (const float*)d_in[15],
        (const float*)d_in[16], (const float*)d_in[17], (const float*)d_in[18],
        (const float*)d_in[19], (const float*)d_in[20], (const float*)d_in[21],
        (const float*)d_in[22], (const float*)d_in[23], (const float*)d_in[24],
        bufA, bufB, wpre, bpre);

    gate1_kernel<<<dim3(4, 128, Bb), 256, 0, stream>>>(
        (const float*)d_in[0], (const float*)d_in[1], (const float*)d_in[2], (const float*)d_in[3],
        (const float*)d_in[4], (const float*)d_in[5], (const float*)d_in[6], bufA);

    dim3 grid(Tt, Bb), blk(256);
    gate_mfma<2, 0><<<grid, blk, 0, stream>>>(bufA, wpre,         bpre,      bufB);
    gate_mfma<4, 0><<<grid, blk, 0, stream>>>(bufB, wpre + 20480, bpre + 32, bufA);
    gate_mfma<8, 1><<<grid, blk, 0, stream>>>(bufA, wpre + 40960, bpre + 64, bufB);

    // GRU reads fp32 gruIn (bufB), writes partials into bufA
    gru_kernel<<<Bb * 8 * 4, 64, 0, stream>>>(
        (const float*)bufB, (const float*)d_in[25], (const float*)d_in[26], (const float*)d_in[27],
        (const float*)d_in[28], (const float*)d_in[29], (float*)bufA);

    out_kernel<<<2048, 256, 0, stream>>>(
        (const float*)bufA, (const float*)d_in[30], (float*)d_out);
}

// Round 8
// 364.126 us; speedup vs baseline: 1.6086x; 1.0356x over previous
//
#include <hip/hip_runtime.h>

#define Bb 8
#define Tt 512
#define Ff 256
#define Cc 16
#define TF (Tt*Ff)
#define TROW 528
#define FROW 272
#define CELL 64
#define WROWB (144*CELL)                           // 9216 B per staged window row
#define BUFBYTES ((size_t)Bb*TROW*FROW*CELL)       // 73,531,392

typedef __attribute__((ext_vector_type(8))) short short8;
typedef __attribute__((ext_vector_type(4))) float f32x4;

typedef const __attribute__((address_space(1))) void* gas1_t;
typedef __attribute__((address_space(3))) void* las3_t;
#define GLOAD_LDS(g, l) __builtin_amdgcn_global_load_lds((gas1_t)(const void*)(g), (las3_t)(void*)(l), 16, 0, 0)

__device__ __forceinline__ float fexp2(float x) { return __builtin_amdgcn_exp2f(x); }

__device__ __forceinline__ float fast_sigmoid(float x) {
    return __builtin_amdgcn_rcpf(1.0f + fexp2(-1.4426950408889634f * x));
}
__device__ __forceinline__ float fast_tanh(float x) {
    return 1.0f - 2.0f * __builtin_amdgcn_rcpf(fexp2(2.8853900817779268f * x) + 1.0f);
}

__device__ __forceinline__ unsigned short bf16_rne(float x) {
    unsigned u = __float_as_uint(x);
    u += 0x7fffu + ((u >> 16) & 1u);
    return (unsigned short)(u >> 16);
}
__device__ __forceinline__ float bf16_to_f(unsigned short h) {
    return __uint_as_float(((unsigned)h) << 16);
}
__device__ __forceinline__ f32x4 mfma_bf16(short8 a, short8 b, f32x4 c) {
    return __builtin_amdgcn_mfma_f32_16x16x32_bf16(a, b, c, 0, 0, 0);
}

// paired helpers (SLP-vectorizable to v_pk_fma_f32)
__device__ __forceinline__ float2 f2fma(float2 a, float s, float2 c) {
    return make_float2(fmaf(a.x, s, c.x), fmaf(a.y, s, c.y));
}
// u pre-scaled by log2(e)
__device__ __forceinline__ float2 sig2(float2 u) {
    float e0 = fexp2(-u.x), e1 = fexp2(-u.y);
    return make_float2(__builtin_amdgcn_rcpf(1.f + e0), __builtin_amdgcn_rcpf(1.f + e1));
}
__device__ __forceinline__ float2 tanh2(float2 u) {
    float e0 = fexp2(u.x + u.x), e1 = fexp2(u.y + u.y);
    return make_float2(1.f - 2.f * __builtin_amdgcn_rcpf(e0 + 1.f),
                       1.f - 2.f * __builtin_amdgcn_rcpf(e1 + 1.f));
}

// ---------- merged setup: blocks 0-2 = BN-fold+split weights for convs 2-4;
// blocks 3..786 = zero halo pads of bufA/bufB ----------
__global__ __launch_bounds__(256)
void setup_all(const float* __restrict__ w2, const float* __restrict__ b2, const float* __restrict__ gm2,
               const float* __restrict__ bt2, const float* __restrict__ mn2, const float* __restrict__ vr2,
               const float* __restrict__ w3, const float* __restrict__ b3, const float* __restrict__ gm3,
               const float* __restrict__ bt3, const float* __restrict__ mn3, const float* __restrict__ vr3,
               const float* __restrict__ w4, const float* __restrict__ b4, const float* __restrict__ gm4,
               const float* __restrict__ bt4, const float* __restrict__ mn4, const float* __restrict__ vr4,
               char* __restrict__ bufA, char* __restrict__ bufB,
               char* __restrict__ wpreAll, float* __restrict__ bpreAll)
{
    const int blk = blockIdx.x;
    const int tid = threadIdx.x;
    if (blk < 3) {
        const float *w, *bias, *gamma, *beta, *mean, *var;
        if (blk == 0)      { w = w2; bias = b2; gamma = gm2; beta = bt2; mean = mn2; var = vr2; }
        else if (blk == 1) { w = w3; bias = b3; gamma = gm3; beta = bt3; mean = mn3; var = vr3; }
        else               { w = w4; bias = b4; gamma = gm4; beta = bt4; mean = mn4; var = vr4; }
        char* wpre = wpreAll + blk * 20480;
        float* bpre = bpreAll + blk * 32;
        if (tid < 32) {
            float s = gamma[tid] * rsqrtf(var[tid] + 1e-5f);
            bpre[tid] = (bias[tid] - mean[tid]) * s + beta[tid];
        }
        for (int i = tid; i < 4608; i += 256) {
            int co = i / 144, r = i - co * 144;
            int ci = r / 9, tap = r - ci * 9;
            float s = gamma[co] * rsqrtf(var[co] + 1e-5f);
            float wv = w[(co * 16 + ci) * 9 + tap] * s;
            unsigned short hi = bf16_rne(wv);
            unsigned short lo = bf16_rne(wv - bf16_to_f(hi));
            int ks = tap >> 1, tp = tap & 1;
            int kl = tp * 16 + ci;
            int qq = kl >> 3, jj = kl & 7;
            int sub = qq ^ (co & 3);
            *(unsigned short*)(wpre + ((0 * 5 + ks) * 32 + co) * 64 + sub * 16 + jj * 2) = hi;
            *(unsigned short*)(wpre + ((1 * 5 + ks) * 32 + co) * 64 + sub * 16 + jj * 2) = lo;
        }
        for (int i = tid; i < 1024; i += 256) {
            int p = i >> 9, rem = i & 511;
            int co = rem >> 4, kl = 16 + (rem & 15);
            int qq = kl >> 3, jj = kl & 7;
            int sub = qq ^ (co & 3);
            *(unsigned short*)(wpre + ((p * 5 + 4) * 32 + co) * 64 + sub * 16 + jj * 2) = 0;
        }
    } else {
        int idx = (blk - 3) * 256 + tid;      // 200704 cells total
        int which = idx >= 100352;
        int r0 = which ? idx - 100352 : idx;
        int b = r0 / 12544, c = r0 - b * 12544;
        int tp, fp;
        if (c < 4352) { int row = c / 272; fp = c - row * 272; tp = row < 8 ? row : 512 + row; }
        else { int c2 = c - 4352; tp = 8 + (c2 >> 4); int fi = c2 & 15; fp = fi < 8 ? fi : 256 + fi; }
        char* base = (which ? bufB : bufA) + ((size_t)(b * TROW + tp) * FROW + fp) * CELL;
        float4 z = make_float4(0.f, 0.f, 0.f, 0.f);
        float4* p = (float4*)base;
        p[0] = z; p[1] = z; p[2] = z; p[3] = z;
    }
}

// ---------- conv1 (CIN=2, dil=1): tiled, LDS-staged, whole-chunk stores ----------
__global__ __launch_bounds__(256)
void gate1_kernel(const float* __restrict__ x, const float* __restrict__ w,
                  const float* __restrict__ bias, const float* __restrict__ gamma,
                  const float* __restrict__ beta, const float* __restrict__ mean,
                  const float* __restrict__ var, char* __restrict__ outBuf)
{
    __shared__ float xs[2][6][66];
    __shared__ float wl[18 * 32];
    __shared__ float bnsL[32], bnoL[32];
    const int f0 = blockIdx.x * 64;
    const int t0 = blockIdx.y * 4;
    const int b  = blockIdx.z;
    const int tid = threadIdx.x;
    const int fl = tid & 63;
    const int tr = (tid >> 6) & 1;
    const int h  = tid >> 7;

    if (tid < 32) {
        float s = gamma[tid] * rsqrtf(var[tid] + 1e-5f);
        bnsL[tid] = s;
        bnoL[tid] = (bias[tid] - mean[tid]) * s + beta[tid];
    }
    for (int i = tid; i < 576; i += 256) {
        int co = i & 31, rest = i >> 5;
        int ci = rest / 9, tap = rest - ci * 9;
        wl[rest * 32 + co] = w[(co * 2 + ci) * 9 + tap];
    }
    for (int i = tid; i < 792; i += 256) {
        int ci = i / 396, r = i - ci * 396;
        int row = r / 66, col = r - row * 66;
        int t_in = t0 + row - 1, f_in = f0 + col - 1;
        float v = 0.f;
        if (t_in >= 0 && t_in < Tt && f_in >= 0 && f_in < Ff)
            v = x[((size_t)(b * 2 + ci) * Tt + t_in) * Ff + f_in];
        xs[ci][row][col] = v;
    }
    __syncthreads();

    float acc[2][16];
    #pragma unroll
    for (int q = 0; q < 2; q++)
        #pragma unroll
        for (int j = 0; j < 16; j++) acc[q][j] = 0.f;

    #pragma unroll
    for (int ci = 0; ci < 2; ci++) {
        float win[4][3];
        #pragma unroll
        for (int r = 0; r < 4; r++)
            #pragma unroll
            for (int c = 0; c < 3; c++)
                win[r][c] = xs[ci][2 * tr + r][fl + c];
        #pragma unroll
        for (int dt = 0; dt < 3; dt++)
            #pragma unroll
            for (int kf = 0; kf < 3; kf++) {
                float xv0 = win[dt][kf];
                float xv1 = win[dt + 1][kf];
                const float* wrow = wl + (ci * 9 + dt * 3 + kf) * 32 + h * 8;
                float wv[16];
                *(float4*)(wv)      = *(const float4*)(wrow);
                *(float4*)(wv + 4)  = *(const float4*)(wrow + 4);
                *(float4*)(wv + 8)  = *(const float4*)(wrow + 16);
                *(float4*)(wv + 12) = *(const float4*)(wrow + 20);
                #pragma unroll
                for (int j = 0; j < 16; j++) {
                    acc[0][j] = fmaf(xv0, wv[j], acc[0][j]);
                    acc[1][j] = fmaf(xv1, wv[j], acc[1][j]);
                }
            }
    }

    #pragma unroll
    for (int q = 0; q < 2; q++) {
        int t = t0 + 2 * tr + q;
        int fp = f0 + fl + 8;
        int sw = fp & 3;
        char* cell = outBuf + ((size_t)(b * TROW + t + 8) * FROW + fp) * CELL;
        unsigned short hi[8], lo[8];
        #pragma unroll
        for (int j = 0; j < 8; j++) {
            int ca = h * 8 + j, cg = 16 + h * 8 + j;
            float av = acc[q][j]     * bnsL[ca] + bnoL[ca];
            float gv = acc[q][8 + j] * bnsL[cg] + bnoL[cg];
            float r = fast_tanh(av) * fast_sigmoid(gv);
            hi[j] = bf16_rne(r);
            lo[j] = bf16_rne(r - bf16_to_f(hi[j]));
        }
        uint4 H, L;
        H.x = (unsigned)hi[0] | ((unsigned)hi[1] << 16);
        H.y = (unsigned)hi[2] | ((unsigned)hi[3] << 16);
        H.z = (unsigned)hi[4] | ((unsigned)hi[5] << 16);
        H.w = (unsigned)hi[6] | ((unsigned)hi[7] << 16);
        L.x = (unsigned)lo[0] | ((unsigned)lo[1] << 16);
        L.y = (unsigned)lo[2] | ((unsigned)lo[3] << 16);
        L.z = (unsigned)lo[4] | ((unsigned)lo[5] << 16);
        L.w = (unsigned)lo[6] | ((unsigned)lo[7] << 16);
        *(uint4*)(cell + ((h)     ^ sw) * 16) = H;
        *(uint4*)(cell + ((2 + h) ^ sw) * 16) = L;
    }
}

// ---------- convs 2-4: MFMA implicit GEMM, bf16 hi/lo 3-pass ----------
// Block = 1t x 128f (2 waves), LDS 27.6 KB -> more blocks/CU for deep
// block-level staging overlap. Epilogue transposes through LDS for
// fully coalesced dwordx4 stores.
template<int DIL, int WRITE_F32>
__global__ __launch_bounds__(128, 3)
void gate_mfma(const char* __restrict__ actIn, const char* __restrict__ wpre,
               const float* __restrict__ bpre, char* __restrict__ outBuf)
{
    __shared__ char actL[3 * WROWB];   // 27648 B (reused as epilogue buffer)
    const int t = blockIdx.x, fh = blockIdx.y, b = blockIdx.z;
    const int tid = threadIdx.x;            // 0..127
    const int wv = tid >> 6, lane = tid & 63;
    const int n = lane & 15, q = lane >> 4;
    const int f0 = fh * 128;                // window start (padded coords)

    // A-fragments (weights) from global (L2-hot), registers
    short8 aH[5][2], aL[5][2];
    #pragma unroll
    for (int ks = 0; ks < 5; ks++)
        #pragma unroll
        for (int ct = 0; ct < 2; ct++) {
            int co = ct * 16 + n;
            int sub = q ^ (co & 3);
            aH[ks][ct] = *(const short8*)(wpre + (size_t)((0 * 5 + ks) * 32 + co) * 64 + sub * 16);
            aL[ks][ct] = *(const short8*)(wpre + (size_t)((5 + ks) * 32 + co) * 64 + sub * 16);
        }

    // stage 3 window rows (t-d, t, t+d) x 144 cells
    #pragma unroll
    for (int r = 0; r < 3; r++) {
        int tp = t + 8 + (r - 1) * DIL;
        const char* src = actIn + ((size_t)(b * TROW + tp) * FROW + f0) * CELL;
        char* dst = actL + r * WROWB;
        #pragma unroll
        for (int i = 0; i < 4; i++)
            GLOAD_LDS(src + (i * 128 + tid) * 16, dst + (i * 128 + wv * 64) * 16);
        if (wv == 0)
            GLOAD_LDS(src + (512 + lane) * 16, dst + 512 * 16);
    }
    __syncthreads();

    const int fbl = wv * 64;
    f32x4 acc[4][2] = {};

    #pragma unroll
    for (int ks = 0; ks < 5; ks++) {
        const int tapA = 2 * ks;
        const int tapB = (2 * ks + 1 > 8) ? 8 : 2 * ks + 1;
        const int rowA = tapA / 3, dfA = (tapA % 3 - 1) * DIL;
        const int rowB = tapB / 3, dfB = (tapB % 3 - 1) * DIL;
        int tapSel = q >> 1;
        int row = tapSel ? rowB : rowA;
        int df  = tapSel ? dfB : dfA;
        int cih = q & 1;
        const char* rbase = actL + row * WROWB;
        #pragma unroll
        for (int nt = 0; nt < 4; nt++) {
            int fp = 8 + fbl + nt * 16 + n + df;    // window-local; (fp&3) == global parity
            const char* cell = rbase + fp * CELL;
            short8 bH = *(const short8*)(cell + ((cih) ^ (fp & 3)) * 16);
            short8 bL = *(const short8*)(cell + ((2 + cih) ^ (fp & 3)) * 16);
            #pragma unroll
            for (int ct = 0; ct < 2; ct++) {
                acc[nt][ct] = mfma_bf16(aH[ks][ct], bH, acc[nt][ct]);
                acc[nt][ct] = mfma_bf16(aL[ks][ct], bH, acc[nt][ct]);
                acc[nt][ct] = mfma_bf16(aH[ks][ct], bL, acc[nt][ct]);
            }
        }
    }

    // epilogue: GLU -> LDS -> coalesced chunk stores
    float4 bA = *(const float4*)(bpre + q * 4);
    float4 bG = *(const float4*)(bpre + 16 + q * 4);
    __syncthreads();   // done reading actL; reuse as staging buffer

    if (WRITE_F32) {
        float* ldsT = (float*)actL;          // [c(16)][f_local(128)]
        #pragma unroll
        for (int nt = 0; nt < 4; nt++) {
            float r[4];
            r[0] = fast_tanh(acc[nt][0].x + bA.x) * fast_sigmoid(acc[nt][1].x + bG.x);
            r[1] = fast_tanh(acc[nt][0].y + bA.y) * fast_sigmoid(acc[nt][1].y + bG.y);
            r[2] = fast_tanh(acc[nt][0].z + bA.z) * fast_sigmoid(acc[nt][1].z + bG.z);
            r[3] = fast_tanh(acc[nt][0].w + bA.w) * fast_sigmoid(acc[nt][1].w + bG.w);
            int fl = fbl + nt * 16 + n;
            #pragma unroll
            for (int j = 0; j < 4; j++)
                ldsT[(q * 4 + j) * 128 + fl] = r[j];
        }
        __syncthreads();
        float* gp = (float*)outBuf;
        #pragma unroll
        for (int k = 0; k < 4; k++) {
            int linear = k * 128 + tid;          // 512 float4 chunks
            int c = linear >> 5, fq = linear & 31;
            *(float4*)(gp + (size_t)(b * 16 + c) * TF + t * Ff + fh * 128 + fq * 4) =
                *(const float4*)(ldsT + c * 128 + fq * 4);
        }
    } else {
        char* ldsO = actL;                   // [f_local(128)][sub(4)][16B]
        #pragma unroll
        for (int nt = 0; nt < 4; nt++) {
            float r[4];
            r[0] = fast_tanh(acc[nt][0].x + bA.x) * fast_sigmoid(acc[nt][1].x + bG.x);
            r[1] = fast_tanh(acc[nt][0].y + bA.y) * fast_sigmoid(acc[nt][1].y + bG.y);
            r[2] = fast_tanh(acc[nt][0].z + bA.z) * fast_sigmoid(acc[nt][1].z + bG.z);
            r[3] = fast_tanh(acc[nt][0].w + bA.w) * fast_sigmoid(acc[nt][1].w + bG.w);
            int fl = fbl + nt * 16 + n;
            int fp = fh * 128 + fl + 8;          // global padded f (for swizzle parity)
            unsigned short h[4], l[4];
            #pragma unroll
            for (int j = 0; j < 4; j++) {
                h[j] = bf16_rne(r[j]);
                l[j] = bf16_rne(r[j] - bf16_to_f(h[j]));
            }
            uint2 hw, lw;
            hw.x = (unsigned)h[0] | ((unsigned)h[1] << 16);
            hw.y = (unsigned)h[2] | ((unsigned)h[3] << 16);
            lw.x = (unsigned)l[0] | ((unsigned)l[1] << 16);
            lw.y = (unsigned)l[2] | ((unsigned)l[3] << 16);
            int inner = (q & 1) * 8;
            *(uint2*)(ldsO + fl * 64 + (((q >> 1) ^ (fp & 3)) * 16) + inner) = hw;
            *(uint2*)(ldsO + fl * 64 + (((2 + (q >> 1)) ^ (fp & 3)) * 16) + inner) = lw;
        }
        __syncthreads();
        char* dstRow = outBuf + ((size_t)(b * TROW + t + 8) * FROW + fh * 128 + 8) * CELL;
        #pragma unroll
        for (int k = 0; k < 4; k++) {
            int idx = k * 128 + tid;             // 512 x 16B chunks, contiguous
            *(uint4*)(dstRow + idx * 16) = *(const uint4*)(ldsO + idx * 16);
        }
    }
}

// ---------- grouped GRU (H=2) + fused out_w partial dot ----------
// LDS-DMA staged (ping-pong, vmcnt(16)); gate math in log2-domain with
// paired float2 FMAs. part layout: [b][g][fsl(4)][tpair(256)][lane(64)][2]
__global__ __launch_bounds__(64)
void gru_kernel(const float* __restrict__ xin, const float* __restrict__ wih,
                const float* __restrict__ whh, const float* __restrict__ bih,
                const float* __restrict__ bhh, const float* __restrict__ out_w,
                float* __restrict__ part)
{
    __shared__ float ldsF[2 * 4096];   // 2 x 16 KB ping-pong
    const int lane = threadIdx.x;
    const int fsl = blockIdx.x & 3;
    const int g = (blockIdx.x >> 2) & 7;
    const int b = blockIdx.x >> 5;

    const float L2E = 1.4426950408889634f;
    // gate pairs: R=(rows 0,1), Z=(2,3), N=(4,5); all pre-scaled by log2(e)
    float2 WiX[3], WiY[3], WhX[3], WhY[3], Bi[3], Bh[3];
    #pragma unroll
    for (int p = 0; p < 3; p++) {
        WiX[p] = make_float2(wih[g * 12 + (2 * p) * 2 + 0] * L2E, wih[g * 12 + (2 * p + 1) * 2 + 0] * L2E);
        WiY[p] = make_float2(wih[g * 12 + (2 * p) * 2 + 1] * L2E, wih[g * 12 + (2 * p + 1) * 2 + 1] * L2E);
        WhX[p] = make_float2(whh[g * 12 + (2 * p) * 2 + 0] * L2E, whh[g * 12 + (2 * p + 1) * 2 + 0] * L2E);
        WhY[p] = make_float2(whh[g * 12 + (2 * p) * 2 + 1] * L2E, whh[g * 12 + (2 * p + 1) * 2 + 1] * L2E);
        Bi[p] = make_float2(bih[g * 6 + 2 * p] * L2E, bih[g * 6 + 2 * p + 1] * L2E);
        Bh[p] = make_float2(bhh[g * 6 + 2 * p] * L2E, bhh[g * 6 + 2 * p + 1] * L2E);
    }
    const float ow0 = out_w[2 * g], ow1 = out_w[2 * g + 1];

    const int sub = lane & 15, cch = (lane >> 4) & 1, tpr = lane >> 5;
    const float* gsrc = xin + ((size_t)(b * Cc + 2 * g + cch) * Tt + tpr) * Ff + fsl * 64 + sub * 4;

    float* poBase = part + ((size_t)((b * 8 + g) * 4 + fsl)) * 32768;

    #define STAGE(bsel, t0s)                                                  \
    {                                                                         \
        char* ldst = (char*)(ldsF + (bsel) * 4096);                           \
        const float* gs = gsrc + (size_t)(t0s) * Ff;                          \
        _Pragma("unroll")                                                     \
        for (int j = 0; j < 16; j++)                                          \
            GLOAD_LDS(gs + 2 * j * Ff, ldst + j * 1024);                      \
    }

    float2 hP = make_float2(0.f, 0.f);
    STAGE(0, 0);
    int buf = 0;
    for (int t0 = 0; t0 < Tt; t0 += 32) {
        if (t0 + 32 < Tt) STAGE(buf ^ 1, t0 + 32);
        __builtin_amdgcn_s_waitcnt(0x4F70);   // vmcnt(16)
        float2 outR[16];
        #pragma unroll
        for (int tt = 0; tt < 32; tt++) {
            const float* cell = ldsF + buf * 4096 + (tt >> 1) * 256 + (tt & 1) * 128;
            float x0 = cell[lane];
            float x1 = cell[64 + lane];
            float2 giR = f2fma(WiY[0], x1, f2fma(WiX[0], x0, Bi[0]));
            float2 giZ = f2fma(WiY[1], x1, f2fma(WiX[1], x0, Bi[1]));
            float2 giN = f2fma(WiY[2], x1, f2fma(WiX[2], x0, Bi[2]));
            float2 ghR = f2fma(WhY[0], hP.y, f2fma(WhX[0], hP.x, Bh[0]));
            float2 ghZ = f2fma(WhY[1], hP.y, f2fma(WhX[1], hP.x, Bh[1]));
            float2 ghN = f2fma(WhY[2], hP.y, f2fma(WhX[2], hP.x, Bh[2]));
            float2 rP = sig2(make_float2(giR.x + ghR.x, giR.y + ghR.y));
            float2 zP = sig2(make_float2(giZ.x + ghZ.x, giZ.y + ghZ.y));
            float2 nP = tanh2(make_float2(fmaf(rP.x, ghN.x, giN.x), fmaf(rP.y, ghN.y, giN.y)));
            // h = n + z*(h - n)
            hP = make_float2(fmaf(zP.x, hP.x - nP.x, nP.x), fmaf(zP.y, hP.y - nP.y, nP.y));
            float o = fmaf(hP.x, ow0, hP.y * ow1);
            if (tt & 1) outR[tt >> 1].y = o; else outR[tt >> 1].x = o;
        }
        #pragma unroll
        for (int j = 0; j < 16; j++)
            *(float2*)(poBase + ((t0 >> 1) + j) * 128 + lane * 2) = outR[j];
        buf ^= 1;
    }
    #undef STAGE
}

// sum 8 group partials (part layout) + out_b -> (B,1,T,F)
__global__ __launch_bounds__(256)
void out_kernel(const float* __restrict__ part, const float* __restrict__ out_b,
                float* __restrict__ out)
{
    int idx = blockIdx.x * 256 + threadIdx.x;    // 524288 total: [b][tpair][f]
    int f = idx & 255;
    int tp = (idx >> 8) & 255;
    int b = idx >> 16;
    int fsl = f >> 6, ln = f & 63;
    const float* base = part + ((size_t)(b * 8) * 4 + fsl) * 32768 + tp * 128 + ln * 2;
    float ob = out_b[0];
    float s0 = ob, s1 = ob;
    #pragma unroll
    for (int g = 0; g < 8; g++) {
        float2 v = *(const float2*)(base + (size_t)g * 131072);
        s0 += v.x; s1 += v.y;
    }
    float* op = out + ((size_t)b * Tt + 2 * tp) * Ff + f;
    op[0] = s0;
    op[Ff] = s1;
}

extern "C" void kernel_launch(void* const* d_in, const int* in_sizes, int n_in,
                              void* d_out, int out_size, void* d_ws, size_t ws_size,
                              hipStream_t stream) {
    char* bufA = (char*)d_ws;
    char* bufB = bufA + BUFBYTES;
    char* wpre = bufB + BUFBYTES;
    float* bpre = (float*)(wpre + 3 * 20480);

    setup_all<<<787, 256, 0, stream>>>(
        (const float*)d_in[7],  (const float*)d_in[8],  (const float*)d_in[9],
        (const float*)d_in[10], (const float*)d_in[11], (const float*)d_in[12],
        (const float*)d_in[13], (const float*)d_in[14], (const float*)d_in[15],
        (const float*)d_in[16], (const float*)d_in[17], (const float*)d_in[18],
        (const float*)d_in[19], (const float*)d_in[20], (const float*)d_in[21],
        (const float*)d_in[22], (const float*)d_in[23], (const float*)d_in[24],
        bufA, bufB, wpre, bpre);

    gate1_kernel<<<dim3(4, 128, Bb), 256, 0, stream>>>(
        (const float*)d_in[0], (const float*)d_in[1], (const float*)d_in[2], (const float*)d_in[3],
        (const float*)d_in[4], (const float*)d_in[5], (const float*)d_in[6], bufA);

    dim3 grid(Tt, 2, Bb), blk(128);
    gate_mfma<2, 0><<<grid, blk, 0, stream>>>(bufA, wpre,         bpre,      bufB);
    gate_mfma<4, 0><<<grid, blk, 0, stream>>>(bufB, wpre + 20480, bpre + 32, bufA);
    gate_mfma<8, 1><<<grid, blk, 0, stream>>>(bufA, wpre + 40960, bpre + 64, bufB);

    // GRU reads fp32 gruIn (bufB), writes partials into bufA
    gru_kernel<<<Bb * 8 * 4, 64, 0, stream>>>(
        (const float*)bufB, (const float*)d_in[25], (const float*)d_in[26], (const float*)d_in[27],
        (const float*)d_in[28], (const float*)d_in[29], (float*)bufA);

    out_kernel<<<2048, 256, 0, stream>>>(
        (const float*)bufA, (const float*)d_in[30], (float*)d_out);
}

// Round 9
// 357.500 us; speedup vs baseline: 1.6384x; 1.0185x over previous
//
#include <hip/hip_runtime.h>

#define Bb 8
#define Tt 512
#define Ff 256
#define Cc 16
#define TF (Tt*Ff)
#define TROW 528
#define FROW 272
#define CELL 64
#define WROWB (144*CELL)                           // 9216 B per staged window row
#define BUFBYTES ((size_t)Bb*TROW*FROW*CELL)       // 73,531,392

typedef __attribute__((ext_vector_type(8))) short short8;
typedef __attribute__((ext_vector_type(4))) float f32x4;

typedef const __attribute__((address_space(1))) void* gas1_t;
typedef __attribute__((address_space(3))) void* las3_t;
#define GLOAD_LDS(g, l) __builtin_amdgcn_global_load_lds((gas1_t)(const void*)(g), (las3_t)(void*)(l), 16, 0, 0)

__device__ __forceinline__ float fexp2(float x) { return __builtin_amdgcn_exp2f(x); }

__device__ __forceinline__ float fast_sigmoid(float x) {
    return __builtin_amdgcn_rcpf(1.0f + fexp2(-1.4426950408889634f * x));
}
__device__ __forceinline__ float fast_tanh(float x) {
    return 1.0f - 2.0f * __builtin_amdgcn_rcpf(fexp2(2.8853900817779268f * x) + 1.0f);
}

__device__ __forceinline__ unsigned short bf16_rne(float x) {
    unsigned u = __float_as_uint(x);
    u += 0x7fffu + ((u >> 16) & 1u);
    return (unsigned short)(u >> 16);
}
__device__ __forceinline__ float bf16_to_f(unsigned short h) {
    return __uint_as_float(((unsigned)h) << 16);
}
__device__ __forceinline__ f32x4 mfma_bf16(short8 a, short8 b, f32x4 c) {
    return __builtin_amdgcn_mfma_f32_16x16x32_bf16(a, b, c, 0, 0, 0);
}

// paired helpers
__device__ __forceinline__ float2 f2fma(float2 a, float s, float2 c) {
    return make_float2(fmaf(a.x, s, c.x), fmaf(a.y, s, c.y));
}
__device__ __forceinline__ float2 sig2(float2 u) {
    float e0 = fexp2(-u.x), e1 = fexp2(-u.y);
    return make_float2(__builtin_amdgcn_rcpf(1.f + e0), __builtin_amdgcn_rcpf(1.f + e1));
}
__device__ __forceinline__ float2 tanh2(float2 u) {
    float e0 = fexp2(u.x + u.x), e1 = fexp2(u.y + u.y);
    return make_float2(1.f - 2.f * __builtin_amdgcn_rcpf(e0 + 1.f),
                       1.f - 2.f * __builtin_amdgcn_rcpf(e1 + 1.f));
}

// ---------- merged setup: blocks 0-2 = BN-fold+split weights for convs 2-4;
// blocks 3..786 = zero halo pads of bufA/bufB ----------
__global__ __launch_bounds__(256)
void setup_all(const float* __restrict__ w2, const float* __restrict__ b2, const float* __restrict__ gm2,
               const float* __restrict__ bt2, const float* __restrict__ mn2, const float* __restrict__ vr2,
               const float* __restrict__ w3, const float* __restrict__ b3, const float* __restrict__ gm3,
               const float* __restrict__ bt3, const float* __restrict__ mn3, const float* __restrict__ vr3,
               const float* __restrict__ w4, const float* __restrict__ b4, const float* __restrict__ gm4,
               const float* __restrict__ bt4, const float* __restrict__ mn4, const float* __restrict__ vr4,
               char* __restrict__ bufA, char* __restrict__ bufB,
               char* __restrict__ wpreAll, float* __restrict__ bpreAll)
{
    const int blk = blockIdx.x;
    const int tid = threadIdx.x;
    if (blk < 3) {
        const float *w, *bias, *gamma, *beta, *mean, *var;
        if (blk == 0)      { w = w2; bias = b2; gamma = gm2; beta = bt2; mean = mn2; var = vr2; }
        else if (blk == 1) { w = w3; bias = b3; gamma = gm3; beta = bt3; mean = mn3; var = vr3; }
        else               { w = w4; bias = b4; gamma = gm4; beta = bt4; mean = mn4; var = vr4; }
        char* wpre = wpreAll + blk * 20480;
        float* bpre = bpreAll + blk * 32;
        if (tid < 32) {
            float s = gamma[tid] * rsqrtf(var[tid] + 1e-5f);
            bpre[tid] = (bias[tid] - mean[tid]) * s + beta[tid];
        }
        for (int i = tid; i < 4608; i += 256) {
            int co = i / 144, r = i - co * 144;
            int ci = r / 9, tap = r - ci * 9;
            float s = gamma[co] * rsqrtf(var[co] + 1e-5f);
            float wv = w[(co * 16 + ci) * 9 + tap] * s;
            unsigned short hi = bf16_rne(wv);
            unsigned short lo = bf16_rne(wv - bf16_to_f(hi));
            int ks = tap >> 1, tp = tap & 1;
            int kl = tp * 16 + ci;
            int qq = kl >> 3, jj = kl & 7;
            int sub = qq ^ (co & 3);
            *(unsigned short*)(wpre + ((0 * 5 + ks) * 32 + co) * 64 + sub * 16 + jj * 2) = hi;
            *(unsigned short*)(wpre + ((1 * 5 + ks) * 32 + co) * 64 + sub * 16 + jj * 2) = lo;
        }
        for (int i = tid; i < 1024; i += 256) {
            int p = i >> 9, rem = i & 511;
            int co = rem >> 4, kl = 16 + (rem & 15);
            int qq = kl >> 3, jj = kl & 7;
            int sub = qq ^ (co & 3);
            *(unsigned short*)(wpre + ((p * 5 + 4) * 32 + co) * 64 + sub * 16 + jj * 2) = 0;
        }
    } else {
        int idx = (blk - 3) * 256 + tid;      // 200704 cells total
        int which = idx >= 100352;
        int r0 = which ? idx - 100352 : idx;
        int b = r0 / 12544, c = r0 - b * 12544;
        int tp, fp;
        if (c < 4352) { int row = c / 272; fp = c - row * 272; tp = row < 8 ? row : 512 + row; }
        else { int c2 = c - 4352; tp = 8 + (c2 >> 4); int fi = c2 & 15; fp = fi < 8 ? fi : 256 + fi; }
        char* base = (which ? bufB : bufA) + ((size_t)(b * TROW + tp) * FROW + fp) * CELL;
        float4 z = make_float4(0.f, 0.f, 0.f, 0.f);
        float4* p = (float4*)base;
        p[0] = z; p[1] = z; p[2] = z; p[3] = z;
    }
}

// ---------- conv1 (CIN=2, dil=1): tiled, LDS-staged, whole-chunk stores ----------
__global__ __launch_bounds__(256)
void gate1_kernel(const float* __restrict__ x, const float* __restrict__ w,
                  const float* __restrict__ bias, const float* __restrict__ gamma,
                  const float* __restrict__ beta, const float* __restrict__ mean,
                  const float* __restrict__ var, char* __restrict__ outBuf)
{
    __shared__ float xs[2][6][66];
    __shared__ float wl[18 * 32];
    __shared__ float bnsL[32], bnoL[32];
    const int f0 = blockIdx.x * 64;
    const int t0 = blockIdx.y * 4;
    const int b  = blockIdx.z;
    const int tid = threadIdx.x;
    const int fl = tid & 63;
    const int tr = (tid >> 6) & 1;
    const int h  = tid >> 7;

    if (tid < 32) {
        float s = gamma[tid] * rsqrtf(var[tid] + 1e-5f);
        bnsL[tid] = s;
        bnoL[tid] = (bias[tid] - mean[tid]) * s + beta[tid];
    }
    for (int i = tid; i < 576; i += 256) {
        int co = i & 31, rest = i >> 5;
        int ci = rest / 9, tap = rest - ci * 9;
        wl[rest * 32 + co] = w[(co * 2 + ci) * 9 + tap];
    }
    for (int i = tid; i < 792; i += 256) {
        int ci = i / 396, r = i - ci * 396;
        int row = r / 66, col = r - row * 66;
        int t_in = t0 + row - 1, f_in = f0 + col - 1;
        float v = 0.f;
        if (t_in >= 0 && t_in < Tt && f_in >= 0 && f_in < Ff)
            v = x[((size_t)(b * 2 + ci) * Tt + t_in) * Ff + f_in];
        xs[ci][row][col] = v;
    }
    __syncthreads();

    float acc[2][16];
    #pragma unroll
    for (int q = 0; q < 2; q++)
        #pragma unroll
        for (int j = 0; j < 16; j++) acc[q][j] = 0.f;

    #pragma unroll
    for (int ci = 0; ci < 2; ci++) {
        float win[4][3];
        #pragma unroll
        for (int r = 0; r < 4; r++)
            #pragma unroll
            for (int c = 0; c < 3; c++)
                win[r][c] = xs[ci][2 * tr + r][fl + c];
        #pragma unroll
        for (int dt = 0; dt < 3; dt++)
            #pragma unroll
            for (int kf = 0; kf < 3; kf++) {
                float xv0 = win[dt][kf];
                float xv1 = win[dt + 1][kf];
                const float* wrow = wl + (ci * 9 + dt * 3 + kf) * 32 + h * 8;
                float wv[16];
                *(float4*)(wv)      = *(const float4*)(wrow);
                *(float4*)(wv + 4)  = *(const float4*)(wrow + 4);
                *(float4*)(wv + 8)  = *(const float4*)(wrow + 16);
                *(float4*)(wv + 12) = *(const float4*)(wrow + 20);
                #pragma unroll
                for (int j = 0; j < 16; j++) {
                    acc[0][j] = fmaf(xv0, wv[j], acc[0][j]);
                    acc[1][j] = fmaf(xv1, wv[j], acc[1][j]);
                }
            }
    }

    #pragma unroll
    for (int q = 0; q < 2; q++) {
        int t = t0 + 2 * tr + q;
        int fp = f0 + fl + 8;
        int sw = fp & 3;
        char* cell = outBuf + ((size_t)(b * TROW + t + 8) * FROW + fp) * CELL;
        unsigned short hi[8], lo[8];
        #pragma unroll
        for (int j = 0; j < 8; j++) {
            int ca = h * 8 + j, cg = 16 + h * 8 + j;
            float av = acc[q][j]     * bnsL[ca] + bnoL[ca];
            float gv = acc[q][8 + j] * bnsL[cg] + bnoL[cg];
            float r = fast_tanh(av) * fast_sigmoid(gv);
            hi[j] = bf16_rne(r);
            lo[j] = bf16_rne(r - bf16_to_f(hi[j]));
        }
        uint4 H, L;
        H.x = (unsigned)hi[0] | ((unsigned)hi[1] << 16);
        H.y = (unsigned)hi[2] | ((unsigned)hi[3] << 16);
        H.z = (unsigned)hi[4] | ((unsigned)hi[5] << 16);
        H.w = (unsigned)hi[6] | ((unsigned)hi[7] << 16);
        L.x = (unsigned)lo[0] | ((unsigned)lo[1] << 16);
        L.y = (unsigned)lo[2] | ((unsigned)lo[3] << 16);
        L.z = (unsigned)lo[4] | ((unsigned)lo[5] << 16);
        L.w = (unsigned)lo[6] | ((unsigned)lo[7] << 16);
        *(uint4*)(cell + ((h)     ^ sw) * 16) = H;
        *(uint4*)(cell + ((2 + h) ^ sw) * 16) = L;
    }
}

// ---------- convs 2-4: MFMA implicit GEMM, bf16 hi/lo 3-pass ----------
// Dilation-strided t-grouping: block = 4 outputs {t0, t0+d, t0+2d, t0+3d}
// (same residue class mod d) x 128 f. 6 staged rows serve all 4 outputs
// (1.5 rows/output) and 960 wave-MFMAs amortize one barrier. 4 waves:
// (tsel = t-pair, fsel = 64-f strip). LDS 55 KB -> 2 blocks/CU.
template<int DIL, int WRITE_F32>
__global__ __launch_bounds__(256, 2)
void gate_mfma(const char* __restrict__ actIn, const char* __restrict__ wpre,
               const float* __restrict__ bpre, char* __restrict__ outBuf)
{
    __shared__ char actL[6 * WROWB];   // 55296 B (reused as epilogue buffer)
    const int tg = blockIdx.x, fh = blockIdx.y, b = blockIdx.z;
    const int tid = threadIdx.x;            // 0..255
    const int w = tid >> 6, lane = tid & 63;
    const int n = lane & 15, q = lane >> 4;
    const int tsel = w >> 1, fsel = w & 1;
    constexpr int GPC = 128 / DIL;          // t-groups per residue class
    const int rcl = tg / GPC, m = tg - rcl * GPC;
    const int t0 = rcl + 4 * m * DIL;
    const int f0 = fh * 128;

    // A-fragments (weights) from global (L2-hot), registers
    short8 aH[5][2], aL[5][2];
    #pragma unroll
    for (int ks = 0; ks < 5; ks++)
        #pragma unroll
        for (int ct = 0; ct < 2; ct++) {
            int co = ct * 16 + n;
            int sub = q ^ (co & 3);
            aH[ks][ct] = *(const short8*)(wpre + (size_t)((0 * 5 + ks) * 32 + co) * 64 + sub * 16);
            aL[ks][ct] = *(const short8*)(wpre + (size_t)((5 + ks) * 32 + co) * 64 + sub * 16);
        }

    // stage 6 rows: staged row i holds input t-row t0 + (i-1)*DIL
    #pragma unroll
    for (int i = 0; i < 6; i++) {
        int tp = t0 + 8 + (i - 1) * DIL;
        const char* src = actIn + ((size_t)(b * TROW + tp) * FROW + f0) * CELL;
        char* dst = actL + i * WROWB;
        #pragma unroll
        for (int k = 0; k < 2; k++)
            GLOAD_LDS(src + (k * 256 + tid) * 16, dst + (k * 256 + w * 64) * 16);
        if (tid < 64)
            GLOAD_LDS(src + (512 + lane) * 16, dst + 512 * 16);
    }
    __syncthreads();

    const int fbl = fsel * 64;
    f32x4 acc[2][4][2] = {};   // [tj][nt][ct]

    #pragma unroll
    for (int ks = 0; ks < 5; ks++) {
        const int tapA = 2 * ks;
        const int tapB = (2 * ks + 1 > 8) ? 8 : 2 * ks + 1;
        const int rowA = tapA / 3, dfA = (tapA % 3 - 1) * DIL;
        const int rowB = tapB / 3, dfB = (tapB % 3 - 1) * DIL;
        int tapSel = q >> 1;
        int rowt = tapSel ? rowB : rowA;       // t-tap 0..2
        int df  = tapSel ? dfB : dfA;
        int cih = q & 1;
        #pragma unroll
        for (int tj = 0; tj < 2; tj++) {
            const int jj = 2 * tsel + tj;      // output index 0..3
            const char* rbase = actL + (jj + rowt) * WROWB;
            #pragma unroll
            for (int nt = 0; nt < 4; nt++) {
                int fp = 8 + fbl + nt * 16 + n + df;   // window-local; (fp&3)==global parity
                const char* cell = rbase + fp * CELL;
                short8 bH = *(const short8*)(cell + ((cih) ^ (fp & 3)) * 16);
                short8 bL = *(const short8*)(cell + ((2 + cih) ^ (fp & 3)) * 16);
                #pragma unroll
                for (int ct = 0; ct < 2; ct++) {
                    acc[tj][nt][ct] = mfma_bf16(aH[ks][ct], bH, acc[tj][nt][ct]);
                    acc[tj][nt][ct] = mfma_bf16(aL[ks][ct], bH, acc[tj][nt][ct]);
                    acc[tj][nt][ct] = mfma_bf16(aH[ks][ct], bL, acc[tj][nt][ct]);
                }
            }
        }
    }

    // epilogue: GLU -> LDS -> coalesced chunk stores (4 t-rows)
    float4 bA = *(const float4*)(bpre + q * 4);
    float4 bG = *(const float4*)(bpre + 16 + q * 4);
    __syncthreads();   // done reading actL; reuse as staging buffer

    if (WRITE_F32) {
        float* ldsT = (float*)actL;          // [jj(4)][c(16)][f_local(128)]
        #pragma unroll
        for (int tj = 0; tj < 2; tj++) {
            const int jj = 2 * tsel + tj;
            #pragma unroll
            for (int nt = 0; nt < 4; nt++) {
                float r[4];
                r[0] = fast_tanh(acc[tj][nt][0].x + bA.x) * fast_sigmoid(acc[tj][nt][1].x + bG.x);
                r[1] = fast_tanh(acc[tj][nt][0].y + bA.y) * fast_sigmoid(acc[tj][nt][1].y + bG.y);
                r[2] = fast_tanh(acc[tj][nt][0].z + bA.z) * fast_sigmoid(acc[tj][nt][1].z + bG.z);
                r[3] = fast_tanh(acc[tj][nt][0].w + bA.w) * fast_sigmoid(acc[tj][nt][1].w + bG.w);
                int fl = fbl + nt * 16 + n;
                #pragma unroll
                for (int j = 0; j < 4; j++)
                    ldsT[(jj * 16 + q * 4 + j) * 128 + fl] = r[j];
            }
        }
        __syncthreads();
        float* gp = (float*)outBuf;
        #pragma unroll
        for (int k = 0; k < 8; k++) {
            int linear = k * 256 + tid;          // 2048 float4 chunks: [jj][c][fq(32)]
            int jj2 = linear >> 9;
            int rem = linear & 511;
            int c = rem >> 5, fq = rem & 31;
            int tt = t0 + jj2 * DIL;
            *(float4*)(gp + (size_t)(b * 16 + c) * TF + tt * Ff + fh * 128 + fq * 4) =
                *(const float4*)(ldsT + (jj2 * 16 + c) * 128 + fq * 4);
        }
    } else {
        char* ldsO = actL;                   // [jj(4)][f_local(128)][64B]
        #pragma unroll
        for (int tj = 0; tj < 2; tj++) {
            const int jj = 2 * tsel + tj;
            #pragma unroll
            for (int nt = 0; nt < 4; nt++) {
                float r[4];
                r[0] = fast_tanh(acc[tj][nt][0].x + bA.x) * fast_sigmoid(acc[tj][nt][1].x + bG.x);
                r[1] = fast_tanh(acc[tj][nt][0].y + bA.y) * fast_sigmoid(acc[tj][nt][1].y + bG.y);
                r[2] = fast_tanh(acc[tj][nt][0].z + bA.z) * fast_sigmoid(acc[tj][nt][1].z + bG.z);
                r[3] = fast_tanh(acc[tj][nt][0].w + bA.w) * fast_sigmoid(acc[tj][nt][1].w + bG.w);
                int fl = fbl + nt * 16 + n;
                int fp = fh * 128 + fl + 8;          // global padded f (swizzle parity)
                unsigned short h[4], l[4];
                #pragma unroll
                for (int j = 0; j < 4; j++) {
                    h[j] = bf16_rne(r[j]);
                    l[j] = bf16_rne(r[j] - bf16_to_f(h[j]));
                }
                uint2 hw, lw;
                hw.x = (unsigned)h[0] | ((unsigned)h[1] << 16);
                hw.y = (unsigned)h[2] | ((unsigned)h[3] << 16);
                lw.x = (unsigned)l[0] | ((unsigned)l[1] << 16);
                lw.y = (unsigned)l[2] | ((unsigned)l[3] << 16);
                int inner = (q & 1) * 8;
                char* base = ldsO + (jj * 128 + fl) * 64;
                *(uint2*)(base + (((q >> 1) ^ (fp & 3)) * 16) + inner) = hw;
                *(uint2*)(base + (((2 + (q >> 1)) ^ (fp & 3)) * 16) + inner) = lw;
            }
        }
        __syncthreads();
        #pragma unroll
        for (int k = 0; k < 8; k++) {
            int linear = k * 256 + tid;          // 2048 x 16B chunks, 512 per t-row
            int jj2 = linear >> 9;
            int idx = linear & 511;
            int tt = t0 + jj2 * DIL;
            char* dstRow = outBuf + ((size_t)(b * TROW + tt + 8) * FROW + fh * 128 + 8) * CELL;
            *(uint4*)(dstRow + idx * 16) = *(const uint4*)(ldsO + linear * 16);
        }
    }
}

// ---------- grouped GRU (H=2) + fused out_w partial dot ----------
// LDS-DMA staged (ping-pong, vmcnt(16)); gate math in log2-domain.
// part layout: [b][g][fsl(4)][tpair(256)][lane(64)][2]
__global__ __launch_bounds__(64)
void gru_kernel(const float* __restrict__ xin, const float* __restrict__ wih,
                const float* __restrict__ whh, const float* __restrict__ bih,
                const float* __restrict__ bhh, const float* __restrict__ out_w,
                float* __restrict__ part)
{
    __shared__ float ldsF[2 * 4096];   // 2 x 16 KB ping-pong
    const int lane = threadIdx.x;
    const int fsl = blockIdx.x & 3;
    const int g = (blockIdx.x >> 2) & 7;
    const int b = blockIdx.x >> 5;

    const float L2E = 1.4426950408889634f;
    float2 WiX[3], WiY[3], WhX[3], WhY[3], Bi[3], Bh[3];
    #pragma unroll
    for (int p = 0; p < 3; p++) {
        WiX[p] = make_float2(wih[g * 12 + (2 * p) * 2 + 0] * L2E, wih[g * 12 + (2 * p + 1) * 2 + 0] * L2E);
        WiY[p] = make_float2(wih[g * 12 + (2 * p) * 2 + 1] * L2E, wih[g * 12 + (2 * p + 1) * 2 + 1] * L2E);
        WhX[p] = make_float2(whh[g * 12 + (2 * p) * 2 + 0] * L2E, whh[g * 12 + (2 * p + 1) * 2 + 0] * L2E);
        WhY[p] = make_float2(whh[g * 12 + (2 * p) * 2 + 1] * L2E, whh[g * 12 + (2 * p + 1) * 2 + 1] * L2E);
        Bi[p] = make_float2(bih[g * 6 + 2 * p] * L2E, bih[g * 6 + 2 * p + 1] * L2E);
        Bh[p] = make_float2(bhh[g * 6 + 2 * p] * L2E, bhh[g * 6 + 2 * p + 1] * L2E);
    }
    const float ow0 = out_w[2 * g], ow1 = out_w[2 * g + 1];

    const int sub = lane & 15, cch = (lane >> 4) & 1, tpr = lane >> 5;
    const float* gsrc = xin + ((size_t)(b * Cc + 2 * g + cch) * Tt + tpr) * Ff + fsl * 64 + sub * 4;

    float* poBase = part + ((size_t)((b * 8 + g) * 4 + fsl)) * 32768;

    #define STAGE(bsel, t0s)                                                  \
    {                                                                         \
        char* ldst = (char*)(ldsF + (bsel) * 4096);                           \
        const float* gs = gsrc + (size_t)(t0s) * Ff;                          \
        _Pragma("unroll")                                                     \
        for (int j = 0; j < 16; j++)                                          \
            GLOAD_LDS(gs + 2 * j * Ff, ldst + j * 1024);                      \
    }

    float2 hP = make_float2(0.f, 0.f);
    STAGE(0, 0);
    int buf = 0;
    for (int t0 = 0; t0 < Tt; t0 += 32) {
        if (t0 + 32 < Tt) STAGE(buf ^ 1, t0 + 32);
        __builtin_amdgcn_s_waitcnt(0x4F70);   // vmcnt(16)
        float2 outR[16];
        #pragma unroll
        for (int tt = 0; tt < 32; tt++) {
            const float* cell = ldsF + buf * 4096 + (tt >> 1) * 256 + (tt & 1) * 128;
            float x0 = cell[lane];
            float x1 = cell[64 + lane];
            float2 giR = f2fma(WiY[0], x1, f2fma(WiX[0], x0, Bi[0]));
            float2 giZ = f2fma(WiY[1], x1, f2fma(WiX[1], x0, Bi[1]));
            float2 giN = f2fma(WiY[2], x1, f2fma(WiX[2], x0, Bi[2]));
            float2 ghR = f2fma(WhY[0], hP.y, f2fma(WhX[0], hP.x, Bh[0]));
            float2 ghZ = f2fma(WhY[1], hP.y, f2fma(WhX[1], hP.x, Bh[1]));
            float2 ghN = f2fma(WhY[2], hP.y, f2fma(WhX[2], hP.x, Bh[2]));
            float2 rP = sig2(make_float2(giR.x + ghR.x, giR.y + ghR.y));
            float2 zP = sig2(make_float2(giZ.x + ghZ.x, giZ.y + ghZ.y));
            float2 nP = tanh2(make_float2(fmaf(rP.x, ghN.x, giN.x), fmaf(rP.y, ghN.y, giN.y)));
            hP = make_float2(fmaf(zP.x, hP.x - nP.x, nP.x), fmaf(zP.y, hP.y - nP.y, nP.y));
            float o = fmaf(hP.x, ow0, hP.y * ow1);
            if (tt & 1) outR[tt >> 1].y = o; else outR[tt >> 1].x = o;
        }
        #pragma unroll
        for (int j = 0; j < 16; j++)
            *(float2*)(poBase + ((t0 >> 1) + j) * 128 + lane * 2) = outR[j];
        buf ^= 1;
    }
    #undef STAGE
}

// sum 8 group partials (part layout) + out_b -> (B,1,T,F)
__global__ __launch_bounds__(256)
void out_kernel(const float* __restrict__ part, const float* __restrict__ out_b,
                float* __restrict__ out)
{
    int idx = blockIdx.x * 256 + threadIdx.x;    // 524288 total: [b][tpair][f]
    int f = idx & 255;
    int tp = (idx >> 8) & 255;
    int b = idx >> 16;
    int fsl = f >> 6, ln = f & 63;
    const float* base = part + ((size_t)(b * 8) * 4 + fsl) * 32768 + tp * 128 + ln * 2;
    float ob = out_b[0];
    float s0 = ob, s1 = ob;
    #pragma unroll
    for (int g = 0; g < 8; g++) {
        float2 v = *(const float2*)(base + (size_t)g * 131072);
        s0 += v.x; s1 += v.y;
    }
    float* op = out + ((size_t)b * Tt + 2 * tp) * Ff + f;
    op[0] = s0;
    op[Ff] = s1;
}

extern "C" void kernel_launch(void* const* d_in, const int* in_sizes, int n_in,
                              void* d_out, int out_size, void* d_ws, size_t ws_size,
                              hipStream_t stream) {
    char* bufA = (char*)d_ws;
    char* bufB = bufA + BUFBYTES;
    char* wpre = bufB + BUFBYTES;
    float* bpre = (float*)(wpre + 3 * 20480);

    setup_all<<<787, 256, 0, stream>>>(
        (const float*)d_in[7],  (const float*)d_in[8],  (const float*)d_in[9],
        (const float*)d_in[10], (const float*)d_in[11], (const float*)d_in[12],
        (const float*)d_in[13], (const float*)d_in[14], (const float*)d_in[15],
        (const float*)d_in[16], (const float*)d_in[17], (const float*)d_in[18],
        (const float*)d_in[19], (const float*)d_in[20], (const float*)d_in[21],
        (const float*)d_in[22], (const float*)d_in[23], (const float*)d_in[24],
        bufA, bufB, wpre, bpre);

    gate1_kernel<<<dim3(4, 128, Bb), 256, 0, stream>>>(
        (const float*)d_in[0], (const float*)d_in[1], (const float*)d_in[2], (const float*)d_in[3],
        (const float*)d_in[4], (const float*)d_in[5], (const float*)d_in[6], bufA);

    dim3 grid(128, 2, Bb), blk(256);
    gate_mfma<2, 0><<<grid, blk, 0, stream>>>(bufA, wpre,         bpre,      bufB);
    gate_mfma<4, 0><<<grid, blk, 0, stream>>>(bufB, wpre + 20480, bpre + 32, bufA);
    gate_mfma<8, 1><<<grid, blk, 0, stream>>>(bufA, wpre + 40960, bpre + 64, bufB);

    // GRU reads fp32 gruIn (bufB), writes partials into bufA
    gru_kernel<<<Bb * 8 * 4, 64, 0, stream>>>(
        (const float*)bufB, (const float*)d_in[25], (const float*)d_in[26], (const float*)d_in[27],
        (const float*)d_in[28], (const float*)d_in[29], (float*)bufA);

    out_kernel<<<2048, 256, 0, stream>>>(
        (const float*)bufA, (const float*)d_in[30], (float*)d_out);
}